// Round 10
// baseline (294.440 us; speedup 1.0000x reference)
//
#include <hip/hip_runtime.h>
#include <hip/hip_bf16.h>
#include <math.h>

// MambaBlock: B=4, L=1024, D_MODEL=512, D_INNER=1024, D_STATE=16, D_CONV=4, DT_RANK=32
// fp32 in/out. 9 dispatches:
//  gemm1 (MFMA, fp32-staged) -> conv_silu -> gemm3 splitk+reduce (TRANSPOSED out,
//  xdblT [64][BL], L2-resident) -> dt_softplus (coalesced gemv) ->
//  scan v9 (2 waves per (b,d): each wave scans half the sequence, lane owns 8
//  steps; intra-wave Kogge-Stone + ONE cross-wave LDS combine) ->
//  transpose_cast -> gemm6 (MFMA) -> LN.
#define B_   4
#define L_   1024
#define DM   512
#define DI   1024
#define NS   16
#define XDC  64      // DT_RANK + 2*D_STATE
#define BL   4096    // B_*L_
#define KS   4       // gemm3 split-K factor

typedef short bfrag __attribute__((ext_vector_type(8)));   // 8 bf16
typedef float ffrag __attribute__((ext_vector_type(4)));   // 4 fp32 acc

__device__ __forceinline__ ushort f2bf(float v) {
    __hip_bfloat16 h = __float2bfloat16(v);
    return *(ushort*)&h;
}

// stage 8 elements (16B of bf16) into LDS; F32 => convert fp32 source in-register.
template<bool F32>
__device__ __forceinline__ void stage8(const void* p, size_t eoff, ushort* dst) {
    if constexpr (F32) {
        const float* f = (const float*)p + eoff;
        float4 v0 = *(const float4*)f;
        float4 v1 = *(const float4*)(f + 4);
        *(ushort4*)dst       = make_ushort4(f2bf(v0.x), f2bf(v0.y), f2bf(v0.z), f2bf(v0.w));
        *(ushort4*)(dst + 4) = make_ushort4(f2bf(v1.x), f2bf(v1.y), f2bf(v1.z), f2bf(v1.w));
    } else {
        *(uint4*)dst = *(const uint4*)((const ushort*)p + eoff);
    }
}

// MFMA bf16 TN GEMM: C[M,N] = A[M,K] * B[N,K]^T, fp32 out.
// 128x128 block tile, BK=32, 4 waves (2x2), wave tile 64x64 (4x4 of 16x16x32).
// AF/BF: operand source is fp32 (convert during staging) vs pre-cast bf16.
// EPI: 0 none; 2 C += resid[m*ldc+n]
template<int EPI, bool AF, bool BF>
__global__ __launch_bounds__(256) void gemm_mfma(const void* __restrict__ Ap,
        const void* __restrict__ Bp, float* __restrict__ C,
        int K, int ldc, const float* __restrict__ resid)
{
    __shared__ ushort As[128][40];
    __shared__ ushort Bs[128][40];
    const int tid = threadIdx.x;
    const int lane = tid & 63, wave = tid >> 6;
    const int wm = (wave & 1) * 64, wn = (wave >> 1) * 64;
    const int l15 = lane & 15, quad = lane >> 4;
    const int m0 = blockIdx.y * 128, n0 = blockIdx.x * 128;

    ffrag acc[4][4] = {};

    for (int k0 = 0; k0 < K; k0 += 32) {
        #pragma unroll
        for (int i = 0; i < 2; i++) {
            int chunk = tid + i * 256;
            int row = chunk >> 2, kk8 = (chunk & 3) * 8;
            stage8<AF>(Ap, (size_t)(m0 + row) * K + k0 + kk8, &As[row][kk8]);
            stage8<BF>(Bp, (size_t)(n0 + row) * K + k0 + kk8, &Bs[row][kk8]);
        }
        __syncthreads();
        bfrag af[4], bfv[4];
        #pragma unroll
        for (int i = 0; i < 4; i++) {
            af[i]  = *(const bfrag*)&As[wm + i * 16 + l15][quad * 8];
            bfv[i] = *(const bfrag*)&Bs[wn + i * 16 + l15][quad * 8];
        }
        #pragma unroll
        for (int i = 0; i < 4; i++)
            #pragma unroll
            for (int j = 0; j < 4; j++)
                acc[i][j] = __builtin_amdgcn_mfma_f32_16x16x32_bf16(af[i], bfv[j], acc[i][j], 0, 0, 0);
        __syncthreads();
    }

    #pragma unroll
    for (int i = 0; i < 4; i++) {
        #pragma unroll
        for (int j = 0; j < 4; j++) {
            int n = n0 + wn + j * 16 + l15;
            #pragma unroll
            for (int r = 0; r < 4; r++) {
                int m = m0 + wm + i * 16 + quad * 4 + r;
                float v = acc[i][j][r];
                if (EPI == 2) v += resid[(size_t)m * ldc + n];
                C[(size_t)m * ldc + n] = v;
            }
        }
    }
}

// gemm3 split-K, TRANSPOSED output: part[ks][n][m] = sum over K-chunk of u[m][k]*W[n][k].
// A = uT [K=DI][M=BL], W = x_proj_w [64][DI].
// Block: 32 m-rows x 64 n-cols, K-chunk = DI/KS = 256, BK=16.
// Thread t: owns n = t&63, m-range mg*8..mg*8+7 (mg = t>>6).
__global__ __launch_bounds__(256) void gemm3_splitk(const float* __restrict__ uT,
        const float* __restrict__ xw, float* __restrict__ part)
{
    __shared__ float As[16][33];    // [k][m] 32 m
    __shared__ float Ws[16][68];    // [k][n] 64 n
    const int tid = threadIdx.x;
    const int nn = tid & 63;
    const int mg = tid >> 6;        // 0..3
    const int ks = blockIdx.x, m0 = blockIdx.y * 32;
    const int kbase = ks * (DI / KS);
    float acc[8] = {};

    for (int k0 = 0; k0 < DI / KS; k0 += 16) {
        if (tid < 128) {
            int k = tid >> 3, m4 = (tid & 7) * 4;
            const float4 v = *(const float4*)&uT[(size_t)(kbase + k0 + k) * BL + m0 + m4];
            As[k][m4 + 0] = v.x; As[k][m4 + 1] = v.y;
            As[k][m4 + 2] = v.z; As[k][m4 + 3] = v.w;
        }
        {
            int r = tid >> 2, c4 = (tid & 3) * 4;
            const float4 v = *(const float4*)&xw[(size_t)r * DI + kbase + k0 + c4];
            Ws[c4 + 0][r] = v.x; Ws[c4 + 1][r] = v.y;
            Ws[c4 + 2][r] = v.z; Ws[c4 + 3][r] = v.w;
        }
        __syncthreads();
        #pragma unroll
        for (int kk = 0; kk < 16; kk++) {
            float w = Ws[kk][nn];
            #pragma unroll
            for (int i = 0; i < 8; i++)
                acc[i] = fmaf(As[kk][mg * 8 + i], w, acc[i]);
        }
        __syncthreads();
    }

    float* pp = part + (size_t)ks * 64 * BL + (size_t)nn * BL + m0 + mg * 8;
    *(float4*)&pp[0] = make_float4(acc[0], acc[1], acc[2], acc[3]);
    *(float4*)&pp[4] = make_float4(acc[4], acc[5], acc[6], acc[7]);
}

// reduce KS transposed partials -> xdblT [64][BL] fp32.
__global__ __launch_bounds__(256) void gemm3_reduce(const float* __restrict__ part,
        float* __restrict__ xdblT)
{
    int i = blockIdx.x * 256 + threadIdx.x;     // over 64*BL/4
    const float4* p0 = (const float4*)part;
    float4 a = p0[i];
    #pragma unroll
    for (int s = 1; s < KS; s++) {
        float4 b = p0[i + (size_t)s * 64 * BL / 4];
        a.x += b.x; a.y += b.y; a.z += b.z; a.w += b.w;
    }
    ((float4*)xdblT)[i] = a;
}

// delta[d][bl] = softplus(sum_k dtw[d][k] * xdblT[k][bl] + bias[d])
// Block: 4 waves; wave w owns d = blockIdx.y*4 + w. Thread owns one float4 of bl.
// All loads coalesced (row k of xdblT, 1KB per wave per k); xdblT is L2-resident.
__global__ __launch_bounds__(256) void dt_softplus(const float* __restrict__ xdblT,
        const float* __restrict__ dtw, const float* __restrict__ bias,
        float* __restrict__ deltaT)
{
    const int tid = threadIdx.x;
    const int lane = tid & 63;
    const int bl = blockIdx.x * 256 + lane * 4;

    int d = blockIdx.y * 4 + (tid >> 6);
    d = __builtin_amdgcn_readfirstlane(d);
    float wreg[32];
    {
        const float4* wp = (const float4*)(dtw + (size_t)d * 32);
        #pragma unroll
        for (int k = 0; k < 8; k++) *(float4*)&wreg[k * 4] = wp[k];
    }
    const float bb = bias[d];

    float4 acc = make_float4(bb, bb, bb, bb);
    #pragma unroll
    for (int k = 0; k < 32; k++) {
        float4 v = *(const float4*)&xdblT[(size_t)k * BL + bl];
        float w = wreg[k];
        acc.x = fmaf(w, v.x, acc.x);
        acc.y = fmaf(w, v.y, acc.y);
        acc.z = fmaf(w, v.z, acc.z);
        acc.w = fmaf(w, v.w, acc.w);
    }
    float4 o;
    o.x = (acc.x > 20.f) ? acc.x : __logf(1.f + __expf(acc.x));
    o.y = (acc.y > 20.f) ? acc.y : __logf(1.f + __expf(acc.y));
    o.z = (acc.z > 20.f) ? acc.z : __logf(1.f + __expf(acc.z));
    o.w = (acc.w > 20.f) ? acc.w : __logf(1.f + __expf(acc.w));
    *(float4*)&deltaT[(size_t)d * BL + bl] = o;
}

// depthwise causal conv (k=4) + bias + SiLU, channel-major, 4 outputs/thread.
__global__ __launch_bounds__(256) void conv_silu(const float* __restrict__ xzT,
        const float* __restrict__ cw, const float* __restrict__ cb,
        float* __restrict__ uT)
{
    int i = blockIdx.x * 256 + threadIdx.x;     // over DI*BL/4
    int d  = i >> 10;
    int q  = i & 1023;
    int bl = q * 4;
    int l  = bl & (L_ - 1);
    const float* row = xzT + (size_t)d * BL;
    float4 cur = *(const float4*)&row[bl];
    float4 prev = make_float4(0.f, 0.f, 0.f, 0.f);
    if (l != 0) prev = *(const float4*)&row[bl - 4];
    float v[7] = { prev.y, prev.z, prev.w, cur.x, cur.y, cur.z, cur.w };
    float w0 = cw[d * 4 + 0], w1 = cw[d * 4 + 1], w2 = cw[d * 4 + 2], w3 = cw[d * 4 + 3];
    float bias = cb[d];
    float4 o;
    o.x = bias + w0 * v[0] + w1 * v[1] + w2 * v[2] + w3 * v[3];
    o.y = bias + w0 * v[1] + w1 * v[2] + w2 * v[3] + w3 * v[4];
    o.z = bias + w0 * v[2] + w1 * v[3] + w2 * v[4] + w3 * v[5];
    o.w = bias + w0 * v[3] + w1 * v[4] + w2 * v[5] + w3 * v[6];
    o.x = o.x / (1.f + __expf(-o.x));
    o.y = o.y / (1.f + __expf(-o.y));
    o.z = o.z / (1.f + __expf(-o.z));
    o.w = o.w / (1.f + __expf(-o.w));
    *(float4*)&uT[(size_t)d * BL + bl] = o;
}

// ---- selective scan v9: 2 waves per (b,d), halved per-wave depth ----
// Block = 128 threads = 2 waves, one (b,d). Wave w owns timesteps
// [w*512, w*512+512); lane owns 8 contiguous steps; all 16 n-states in regs.
//  - B/C read DIRECTLY from xdblT rows (L2-resident, lane-contiguous 32B lines)
//  - phase 1: 8-step local affine summary (a = exp(Acoef*sum_dv), bb = h_end|0)
//  - intra-wave Kogge-Stone shfl scan (6 rounds)
//  - cross-wave combine: wave0 lane63 writes inclusive bb -> LDS (16 floats),
//    ONE __syncthreads, h0 = a_excl*h0w + b_excl (h0w = 0 for wave0)
//  - phase 2: 8-step rescan + local C-contraction; gate; store
__global__ __launch_bounds__(128) void scan_fused(const float* __restrict__ deltaT,
        const float* __restrict__ uT, const float* __restrict__ xdblT,
        const float* __restrict__ xzT, const float* __restrict__ A_log,
        const float* __restrict__ Dp, float* __restrict__ yT)
{
    __shared__ float btot[16];

    const int tid = threadIdx.x;
    const int lane = tid & 63;
    const int w = tid >> 6;            // half index 0/1
    const int bd = blockIdx.x;
    const int d = bd & (DI - 1);
    const int b = bd >> 10;

    float Acoef[16];
    {
        const float4* ap = (const float4*)(A_log + d * NS);
        #pragma unroll
        for (int i = 0; i < 4; i++) {
            float4 v = ap[i];
            Acoef[i * 4 + 0] = -__expf(v.x); Acoef[i * 4 + 1] = -__expf(v.y);
            Acoef[i * 4 + 2] = -__expf(v.z); Acoef[i * 4 + 3] = -__expf(v.w);
        }
    }
    const float Dd = Dp[d];

    const int off0 = w * 512 + lane * 8;          // within-batch start timestep
    const size_t row_t = (size_t)d * BL + b * L_ + off0;
    const size_t row_z = (size_t)(DI + d) * BL + b * L_ + off0;
    const float* xB = xdblT + (size_t)32 * BL + b * L_ + off0;  // B row n: +n*BL
    const float* xC = xdblT + (size_t)48 * BL + b * L_ + off0;  // C row n: +n*BL

    // load 8 steps of delta, u (lane-contiguous 32B lines)
    float dv[8], uv[8];
    {
        const float4* dp = (const float4*)(deltaT + row_t);
        const float4* up = (const float4*)(uT + row_t);
        #pragma unroll
        for (int i = 0; i < 2; i++) {
            *(float4*)&dv[i * 4] = dp[i];
            *(float4*)&uv[i * 4] = up[i];
        }
    }
    float du[8];
    float sa = 0.f;
    #pragma unroll
    for (int j = 0; j < 8; j++) { du[j] = dv[j] * uv[j]; sa += dv[j]; }

    // ---- phase 1: local summary (a, bb) per n ----
    float a[16], bb[16];
    #pragma unroll
    for (int n = 0; n < 16; n++) {
        a[n] = __expf(sa * Acoef[n]);
        const float4* bp = (const float4*)(xB + (size_t)n * BL);
        float acc;
        #pragma unroll
        for (int i = 0; i < 2; i++) {
            float4 Bv = bp[i];
            if (i == 0) acc = du[0] * Bv.x;
            else        acc = fmaf(__expf(dv[i * 4] * Acoef[n]), acc, du[i * 4] * Bv.x);
            acc = fmaf(__expf(dv[i * 4 + 1] * Acoef[n]), acc, du[i * 4 + 1] * Bv.y);
            acc = fmaf(__expf(dv[i * 4 + 2] * Acoef[n]), acc, du[i * 4 + 2] * Bv.z);
            acc = fmaf(__expf(dv[i * 4 + 3] * Acoef[n]), acc, du[i * 4 + 3] * Bv.w);
        }
        bb[n] = acc;
    }

    // ---- intra-wave Kogge-Stone inclusive scan over 64 lanes ----
    #pragma unroll
    for (int off = 1; off < 64; off <<= 1) {
        #pragma unroll
        for (int n = 0; n < 16; n++) {
            float pa = __shfl_up(a[n], off);
            float pb = __shfl_up(bb[n], off);
            if (lane >= off) {
                bb[n] = fmaf(a[n], pb, bb[n]);   // uses OLD a (newer ∘ older)
                a[n] *= pa;
            }
        }
    }

    // ---- cross-wave combine ----
    if (w == 0 && lane == 63) {
        #pragma unroll
        for (int n = 0; n < 16; n++) btot[n] = bb[n];
    }
    __syncthreads();

    // h0 for this lane's 8 steps: h = a_excl * h0_wave + b_excl
    float h[16];
    #pragma unroll
    for (int n = 0; n < 16; n++) {
        float pa = __shfl_up(a[n], 1);
        float pb = __shfl_up(bb[n], 1);
        float ae = (lane == 0) ? 1.f : pa;
        float be = (lane == 0) ? 0.f : pb;
        float h0w = (w == 0) ? 0.f : btot[n];
        h[n] = fmaf(ae, h0w, be);
    }

    // ---- phase 2: rescan 8 steps + C-contraction ----
    float s[8];
    #pragma unroll
    for (int j = 0; j < 8; j++) s[j] = 0.f;
    #pragma unroll
    for (int n = 0; n < 16; n++) {
        const float4* bp = (const float4*)(xB + (size_t)n * BL);
        const float4* cp = (const float4*)(xC + (size_t)n * BL);
        float hn = h[n];
        #pragma unroll
        for (int i = 0; i < 2; i++) {
            float4 Bv = bp[i];
            float4 Cv = cp[i];
            hn = fmaf(__expf(dv[i * 4 + 0] * Acoef[n]), hn, du[i * 4 + 0] * Bv.x);
            s[i * 4 + 0] = fmaf(hn, Cv.x, s[i * 4 + 0]);
            hn = fmaf(__expf(dv[i * 4 + 1] * Acoef[n]), hn, du[i * 4 + 1] * Bv.y);
            s[i * 4 + 1] = fmaf(hn, Cv.y, s[i * 4 + 1]);
            hn = fmaf(__expf(dv[i * 4 + 2] * Acoef[n]), hn, du[i * 4 + 2] * Bv.z);
            s[i * 4 + 2] = fmaf(hn, Cv.z, s[i * 4 + 2]);
            hn = fmaf(__expf(dv[i * 4 + 3] * Acoef[n]), hn, du[i * 4 + 3] * Bv.w);
            s[i * 4 + 3] = fmaf(hn, Cv.w, s[i * 4 + 3]);
        }
    }

    // gate + store (lane-contiguous 32B lines)
    {
        const float4* zp = (const float4*)(xzT + row_z);
        float4* yp = (float4*)(yT + row_t);
        #pragma unroll
        for (int i = 0; i < 2; i++) {
            float4 zv = zp[i];
            float4 yv;
            float v0 = s[i * 4 + 0] + uv[i * 4 + 0] * Dd;
            float v1 = s[i * 4 + 1] + uv[i * 4 + 1] * Dd;
            float v2 = s[i * 4 + 2] + uv[i * 4 + 2] * Dd;
            float v3 = s[i * 4 + 3] + uv[i * 4 + 3] * Dd;
            yv.x = v0 * (zv.x / (1.f + __expf(-zv.x)));
            yv.y = v1 * (zv.y / (1.f + __expf(-zv.y)));
            yv.z = v2 * (zv.z / (1.f + __expf(-zv.z)));
            yv.w = v3 * (zv.w / (1.f + __expf(-zv.w)));
            yp[i] = yv;
        }
    }
}

// yT fp32 [DI][BL] -> yB bf16 [BL][DI], 64x64 LDS tiles.
__global__ __launch_bounds__(256) void transpose_cast(const float* __restrict__ yT,
        ushort* __restrict__ yB)
{
    __shared__ float t[64][65];
    const int bl0 = blockIdx.x * 64, d0 = blockIdx.y * 64;
    const int tid = threadIdx.x;
    #pragma unroll
    for (int i = 0; i < 4; i++) {
        int chunk = tid + i * 256;
        int dr = chunk >> 4, c4 = (chunk & 15) * 4;
        const float4 v = *(const float4*)&yT[(size_t)(d0 + dr) * BL + bl0 + c4];
        t[dr][c4 + 0] = v.x; t[dr][c4 + 1] = v.y;
        t[dr][c4 + 2] = v.z; t[dr][c4 + 3] = v.w;
    }
    __syncthreads();
    #pragma unroll
    for (int i = 0; i < 4; i++) {
        int chunk = tid + i * 256;
        int br = chunk >> 4, dc4 = (chunk & 15) * 4;
        ushort4 o;
        o.x = f2bf(t[dc4 + 0][br]); o.y = f2bf(t[dc4 + 1][br]);
        o.z = f2bf(t[dc4 + 2][br]); o.w = f2bf(t[dc4 + 3][br]);
        *(ushort4*)&yB[(size_t)(bl0 + br) * DI + d0 + dc4] = o;
    }
}

// LayerNorm over last dim (512), one block per row, fp32 out.
__global__ __launch_bounds__(256) void ln_kernel(const float* __restrict__ r,
        const float* __restrict__ lnw, const float* __restrict__ lnb,
        float* __restrict__ out)
{
    int row = blockIdx.x;
    const float* rr = r + (size_t)row * DM;
    float v0 = rr[threadIdx.x], v1 = rr[threadIdx.x + 256];
    float s = v0 + v1, s2 = v0 * v0 + v1 * v1;
    #pragma unroll
    for (int off = 32; off > 0; off >>= 1) {
        s  += __shfl_down(s, off);
        s2 += __shfl_down(s2, off);
    }
    __shared__ float ls[4], ls2[4];
    __shared__ float mu_s, rstd_s;
    int wid = threadIdx.x >> 6, lane = threadIdx.x & 63;
    if (lane == 0) { ls[wid] = s; ls2[wid] = s2; }
    __syncthreads();
    if (threadIdx.x == 0) {
        float S = ls[0] + ls[1] + ls[2] + ls[3];
        float S2 = ls2[0] + ls2[1] + ls2[2] + ls2[3];
        float mu = S * (1.f / DM);
        float var = S2 * (1.f / DM) - mu * mu;
        mu_s = mu;
        rstd_s = rsqrtf(var + 1e-5f);
    }
    __syncthreads();
    float mu = mu_s, rstd = rstd_s;
    out[(size_t)row * DM + threadIdx.x] =
        (v0 - mu) * rstd * lnw[threadIdx.x] + lnb[threadIdx.x];
    out[(size_t)row * DM + threadIdx.x + 256] =
        (v1 - mu) * rstd * lnw[threadIdx.x + 256] + lnb[threadIdx.x + 256];
}

extern "C" void kernel_launch(void* const* d_in, const int* in_sizes, int n_in,
                              void* d_out, int out_size, void* d_ws, size_t ws_size,
                              hipStream_t stream)
{
    const float* x         = (const float*)d_in[0];
    const float* in_proj_w = (const float*)d_in[1];
    const float* conv_w    = (const float*)d_in[2];
    const float* conv_b    = (const float*)d_in[3];
    const float* x_proj_w  = (const float*)d_in[4];
    const float* dt_proj_w = (const float*)d_in[5];
    const float* dt_proj_b = (const float*)d_in[6];
    const float* A_log     = (const float*)d_in[7];
    const float* Dvec      = (const float*)d_in[8];
    const float* out_proj_w= (const float*)d_in[9];
    const float* ln_w      = (const float*)d_in[10];
    const float* ln_b      = (const float*)d_in[11];
    float* out = (float*)d_out;

    // fp32 regions (floats)
    float* ws     = (float*)d_ws;
    float* xzT    = ws;                                  // 2048 x 4096 (32 MB)
    float* uT     = xzT    + (size_t)2048 * BL;          // 1024 x 4096 (16 MB)
    float* xdblT  = uT     + (size_t)DI * BL;            // 64 x 4096   (1 MB)
    float* deltaT = xdblT  + (size_t)XDC * BL;           // 1024 x 4096 (16 MB)
    float* yT     = deltaT + (size_t)DI * BL;            // 1024 x 4096 (16 MB)
    float* r      = yT     + (size_t)DI * BL;            // 4096 x 512  (8 MB)
    // aliases over time-dead regions:
    float*  xdblp = yT;                                  // KS*64*BL fl = 4 MB, gemm3 partials
    ushort* yB    = (ushort*)deltaT;                     // deltaT dead after scan

    dim3 blk(256);

    // 1) xzT[e][bl] = in_proj_w @ x^T : M=2048, N=4096, K=512 (MFMA, fp32 staged)
    gemm_mfma<0, true, true><<<dim3(BL / 128, 2048 / 128), blk, 0, stream>>>(
        in_proj_w, x, xzT, DM, BL, nullptr);

    // 2) uT = silu(causal_conv(xsT) + cb)
    conv_silu<<<(DI * BL / 4) / 256, blk, 0, stream>>>(xzT, conv_w, conv_b, uT);

    // 3) xdblT = (u @ x_proj_w^T)^T : transposed split-K partials + reduce
    gemm3_splitk<<<dim3(KS, BL / 32), blk, 0, stream>>>(uT, x_proj_w, xdblp);
    gemm3_reduce<<<(64 * BL / 4) / 256, blk, 0, stream>>>(xdblp, xdblT);

    // 4) deltaT[d][bl] = softplus(dtw[d] . xdblT[0:32][bl] + b) : coalesced gemv
    dt_softplus<<<dim3(BL / 256, DI / 4), blk, 0, stream>>>(
        xdblT, dt_proj_w, dt_proj_b, deltaT);

    // 5) fused selective scan + gate (2 waves per (b,d), cross-wave LDS combine)
    scan_fused<<<B_ * DI, dim3(128), 0, stream>>>(
        deltaT, uT, xdblT, xzT, A_log, Dvec, yT);

    // 6a) yT -> yB (bf16, [bl][d])
    transpose_cast<<<dim3(BL / 64, DI / 64), blk, 0, stream>>>(yT, yB);

    // 6b) r[bl][dm] = y @ out_proj_w^T + x : M=4096, N=512, K=1024 (MFMA, resid epi)
    gemm_mfma<2, false, true><<<dim3(DM / 128, BL / 128), blk, 0, stream>>>(
        yB, out_proj_w, r, DI, DM, x);

    // 7) LayerNorm -> fp32 out
    ln_kernel<<<BL, blk, 0, stream>>>(r, ln_w, ln_b, out);
}

// Round 11
// 279.749 us; speedup vs baseline: 1.0525x; 1.0525x over previous
//
#include <hip/hip_runtime.h>
#include <hip/hip_bf16.h>
#include <math.h>

// MambaBlock: B=4, L=1024, D_MODEL=512, D_INNER=1024, D_STATE=16, D_CONV=4, DT_RANK=32
// fp32 in/out. 8 dispatches:
//  gemm1 (MFMA, fp32-staged) -> conv_silu -> gemm3 splitk+reduce (TRANSPOSED out,
//  xdblT [64][BL], L2-resident) ->
//  scan v10 (= v8 + inline delta: softplus(dtw[d].xdblT[0:32,bl]+b) computed
//  in-kernel with the same coalesced row reads; single-chunk, lane owns 16 steps,
//  ONE Kogge-Stone pass, no LDS, no barriers) -> transpose_cast -> gemm6 -> LN.
#define B_   4
#define L_   1024
#define DM   512
#define DI   1024
#define NS   16
#define XDC  64      // DT_RANK + 2*D_STATE
#define BL   4096    // B_*L_
#define KS   4       // gemm3 split-K factor

typedef short bfrag __attribute__((ext_vector_type(8)));   // 8 bf16
typedef float ffrag __attribute__((ext_vector_type(4)));   // 4 fp32 acc

__device__ __forceinline__ ushort f2bf(float v) {
    __hip_bfloat16 h = __float2bfloat16(v);
    return *(ushort*)&h;
}

// stage 8 elements (16B of bf16) into LDS; F32 => convert fp32 source in-register.
template<bool F32>
__device__ __forceinline__ void stage8(const void* p, size_t eoff, ushort* dst) {
    if constexpr (F32) {
        const float* f = (const float*)p + eoff;
        float4 v0 = *(const float4*)f;
        float4 v1 = *(const float4*)(f + 4);
        *(ushort4*)dst       = make_ushort4(f2bf(v0.x), f2bf(v0.y), f2bf(v0.z), f2bf(v0.w));
        *(ushort4*)(dst + 4) = make_ushort4(f2bf(v1.x), f2bf(v1.y), f2bf(v1.z), f2bf(v1.w));
    } else {
        *(uint4*)dst = *(const uint4*)((const ushort*)p + eoff);
    }
}

// MFMA bf16 TN GEMM: C[M,N] = A[M,K] * B[N,K]^T, fp32 out.
// 128x128 block tile, BK=32, 4 waves (2x2), wave tile 64x64 (4x4 of 16x16x32).
// AF/BF: operand source is fp32 (convert during staging) vs pre-cast bf16.
// EPI: 0 none; 2 C += resid[m*ldc+n]
template<int EPI, bool AF, bool BF>
__global__ __launch_bounds__(256) void gemm_mfma(const void* __restrict__ Ap,
        const void* __restrict__ Bp, float* __restrict__ C,
        int K, int ldc, const float* __restrict__ resid)
{
    __shared__ ushort As[128][40];
    __shared__ ushort Bs[128][40];
    const int tid = threadIdx.x;
    const int lane = tid & 63, wave = tid >> 6;
    const int wm = (wave & 1) * 64, wn = (wave >> 1) * 64;
    const int l15 = lane & 15, quad = lane >> 4;
    const int m0 = blockIdx.y * 128, n0 = blockIdx.x * 128;

    ffrag acc[4][4] = {};

    for (int k0 = 0; k0 < K; k0 += 32) {
        #pragma unroll
        for (int i = 0; i < 2; i++) {
            int chunk = tid + i * 256;
            int row = chunk >> 2, kk8 = (chunk & 3) * 8;
            stage8<AF>(Ap, (size_t)(m0 + row) * K + k0 + kk8, &As[row][kk8]);
            stage8<BF>(Bp, (size_t)(n0 + row) * K + k0 + kk8, &Bs[row][kk8]);
        }
        __syncthreads();
        bfrag af[4], bfv[4];
        #pragma unroll
        for (int i = 0; i < 4; i++) {
            af[i]  = *(const bfrag*)&As[wm + i * 16 + l15][quad * 8];
            bfv[i] = *(const bfrag*)&Bs[wn + i * 16 + l15][quad * 8];
        }
        #pragma unroll
        for (int i = 0; i < 4; i++)
            #pragma unroll
            for (int j = 0; j < 4; j++)
                acc[i][j] = __builtin_amdgcn_mfma_f32_16x16x32_bf16(af[i], bfv[j], acc[i][j], 0, 0, 0);
        __syncthreads();
    }

    #pragma unroll
    for (int i = 0; i < 4; i++) {
        #pragma unroll
        for (int j = 0; j < 4; j++) {
            int n = n0 + wn + j * 16 + l15;
            #pragma unroll
            for (int r = 0; r < 4; r++) {
                int m = m0 + wm + i * 16 + quad * 4 + r;
                float v = acc[i][j][r];
                if (EPI == 2) v += resid[(size_t)m * ldc + n];
                C[(size_t)m * ldc + n] = v;
            }
        }
    }
}

// gemm3 split-K, TRANSPOSED output: part[ks][n][m] = sum over K-chunk of u[m][k]*W[n][k].
// A = uT [K=DI][M=BL], W = x_proj_w [64][DI].
// Block: 32 m-rows x 64 n-cols, K-chunk = DI/KS = 256, BK=16.
// Thread t: owns n = t&63, m-range mg*8..mg*8+7 (mg = t>>6).
__global__ __launch_bounds__(256) void gemm3_splitk(const float* __restrict__ uT,
        const float* __restrict__ xw, float* __restrict__ part)
{
    __shared__ float As[16][33];    // [k][m] 32 m
    __shared__ float Ws[16][68];    // [k][n] 64 n
    const int tid = threadIdx.x;
    const int nn = tid & 63;
    const int mg = tid >> 6;        // 0..3
    const int ks = blockIdx.x, m0 = blockIdx.y * 32;
    const int kbase = ks * (DI / KS);
    float acc[8] = {};

    for (int k0 = 0; k0 < DI / KS; k0 += 16) {
        if (tid < 128) {
            int k = tid >> 3, m4 = (tid & 7) * 4;
            const float4 v = *(const float4*)&uT[(size_t)(kbase + k0 + k) * BL + m0 + m4];
            As[k][m4 + 0] = v.x; As[k][m4 + 1] = v.y;
            As[k][m4 + 2] = v.z; As[k][m4 + 3] = v.w;
        }
        {
            int r = tid >> 2, c4 = (tid & 3) * 4;
            const float4 v = *(const float4*)&xw[(size_t)r * DI + kbase + k0 + c4];
            Ws[c4 + 0][r] = v.x; Ws[c4 + 1][r] = v.y;
            Ws[c4 + 2][r] = v.z; Ws[c4 + 3][r] = v.w;
        }
        __syncthreads();
        #pragma unroll
        for (int kk = 0; kk < 16; kk++) {
            float w = Ws[kk][nn];
            #pragma unroll
            for (int i = 0; i < 8; i++)
                acc[i] = fmaf(As[kk][mg * 8 + i], w, acc[i]);
        }
        __syncthreads();
    }

    float* pp = part + (size_t)ks * 64 * BL + (size_t)nn * BL + m0 + mg * 8;
    *(float4*)&pp[0] = make_float4(acc[0], acc[1], acc[2], acc[3]);
    *(float4*)&pp[4] = make_float4(acc[4], acc[5], acc[6], acc[7]);
}

// reduce KS transposed partials -> xdblT [64][BL] fp32.
__global__ __launch_bounds__(256) void gemm3_reduce(const float* __restrict__ part,
        float* __restrict__ xdblT)
{
    int i = blockIdx.x * 256 + threadIdx.x;     // over 64*BL/4
    const float4* p0 = (const float4*)part;
    float4 a = p0[i];
    #pragma unroll
    for (int s = 1; s < KS; s++) {
        float4 b = p0[i + (size_t)s * 64 * BL / 4];
        a.x += b.x; a.y += b.y; a.z += b.z; a.w += b.w;
    }
    ((float4*)xdblT)[i] = a;
}

// depthwise causal conv (k=4) + bias + SiLU, channel-major, 4 outputs/thread.
__global__ __launch_bounds__(256) void conv_silu(const float* __restrict__ xzT,
        const float* __restrict__ cw, const float* __restrict__ cb,
        float* __restrict__ uT)
{
    int i = blockIdx.x * 256 + threadIdx.x;     // over DI*BL/4
    int d  = i >> 10;
    int q  = i & 1023;
    int bl = q * 4;
    int l  = bl & (L_ - 1);
    const float* row = xzT + (size_t)d * BL;
    float4 cur = *(const float4*)&row[bl];
    float4 prev = make_float4(0.f, 0.f, 0.f, 0.f);
    if (l != 0) prev = *(const float4*)&row[bl - 4];
    float v[7] = { prev.y, prev.z, prev.w, cur.x, cur.y, cur.z, cur.w };
    float w0 = cw[d * 4 + 0], w1 = cw[d * 4 + 1], w2 = cw[d * 4 + 2], w3 = cw[d * 4 + 3];
    float bias = cb[d];
    float4 o;
    o.x = bias + w0 * v[0] + w1 * v[1] + w2 * v[2] + w3 * v[3];
    o.y = bias + w0 * v[1] + w1 * v[2] + w2 * v[3] + w3 * v[4];
    o.z = bias + w0 * v[2] + w1 * v[3] + w2 * v[4] + w3 * v[5];
    o.w = bias + w0 * v[3] + w1 * v[4] + w2 * v[5] + w3 * v[6];
    o.x = o.x / (1.f + __expf(-o.x));
    o.y = o.y / (1.f + __expf(-o.y));
    o.z = o.z / (1.f + __expf(-o.z));
    o.w = o.w / (1.f + __expf(-o.w));
    *(float4*)&uT[(size_t)d * BL + bl] = o;
}

// ---- selective scan v10: v8 + inline delta; single-chunk, barrier-free ----
// Block = 4 waves = 4 (b,d); wave owns one (b,d). Lane k owns timesteps
// [16k, 16k+16); all 16 n-states live in registers.
//  - delta computed inline: softplus(dtw[d] . xdblT[0:32][bl] + bias[d]) with
//    the SAME coalesced row-read pattern as B/C (dtw row wave-uniform -> scalar)
//  - B/C read DIRECTLY from xdblT rows (32+n / 48+n): lane reads its own 64B
//    line; wave covers 4KB contiguous -> line-coalesced, L2-resident (1 MB)
//  - phase 1: 16-step local affine summary (a = exp(Acoef*sum_dv), bb = h_end|0)
//  - ONE Kogge-Stone shfl scan over 64 lanes (6 rounds); h0 = exclusive prefix
//  - phase 2: 16-step rescan + local C-contraction; gate; store
__global__ __launch_bounds__(256) void scan_fused(const float* __restrict__ uT,
        const float* __restrict__ xdblT, const float* __restrict__ xzT,
        const float* __restrict__ A_log, const float* __restrict__ Dp,
        const float* __restrict__ dtw, const float* __restrict__ dtb,
        float* __restrict__ yT)
{
    const int tid = threadIdx.x;
    const int lane = tid & 63;
    const int bd = blockIdx.x * 4 + (tid >> 6);
    const int d = bd & (DI - 1);
    const int b = bd >> 10;

    float Acoef[16];
    {
        const float4* ap = (const float4*)(A_log + d * NS);
        #pragma unroll
        for (int i = 0; i < 4; i++) {
            float4 v = ap[i];
            Acoef[i * 4 + 0] = -__expf(v.x); Acoef[i * 4 + 1] = -__expf(v.y);
            Acoef[i * 4 + 2] = -__expf(v.z); Acoef[i * 4 + 3] = -__expf(v.w);
        }
    }
    const float Dd = Dp[d];

    // dt_proj row: wave-uniform d -> scalar loads
    const int d_u = __builtin_amdgcn_readfirstlane(d);
    float wreg[32];
    {
        const float4* wp = (const float4*)(dtw + (size_t)d_u * 32);
        #pragma unroll
        for (int k = 0; k < 8; k++) *(float4*)&wreg[k * 4] = wp[k];
    }
    const float dbias = dtb[d_u];

    const size_t row_t = (size_t)d * BL + b * L_ + lane * 16;
    const size_t row_z = (size_t)(DI + d) * BL + b * L_ + lane * 16;
    const float* xdt = xdblT + (size_t)b * L_ + lane * 16;           // dt rows: +k*BL
    const float* xB  = xdblT + (size_t)32 * BL + b * L_ + lane * 16; // B row n: +n*BL
    const float* xC  = xdblT + (size_t)48 * BL + b * L_ + lane * 16; // C row n: +n*BL

    // ---- inline delta: dv[j] = softplus(sum_k wreg[k]*xdt[k][j] + dbias) ----
    float dv[16];
    #pragma unroll
    for (int j = 0; j < 16; j++) dv[j] = dbias;
    #pragma unroll
    for (int k = 0; k < 32; k++) {
        const float4* rp = (const float4*)(xdt + (size_t)k * BL);
        float w = wreg[k];
        #pragma unroll
        for (int i = 0; i < 4; i++) {
            float4 v = rp[i];
            dv[i * 4 + 0] = fmaf(w, v.x, dv[i * 4 + 0]);
            dv[i * 4 + 1] = fmaf(w, v.y, dv[i * 4 + 1]);
            dv[i * 4 + 2] = fmaf(w, v.z, dv[i * 4 + 2]);
            dv[i * 4 + 3] = fmaf(w, v.w, dv[i * 4 + 3]);
        }
    }
    #pragma unroll
    for (int j = 0; j < 16; j++)
        dv[j] = (dv[j] > 20.f) ? dv[j] : __logf(1.f + __expf(dv[j]));

    // load u; du = dv*u; sa = sum dv
    float uv[16], du[16];
    {
        const float4* up = (const float4*)(uT + row_t);
        #pragma unroll
        for (int i = 0; i < 4; i++) *(float4*)&uv[i * 4] = up[i];
    }
    float sa = 0.f;
    #pragma unroll
    for (int j = 0; j < 16; j++) { du[j] = dv[j] * uv[j]; sa += dv[j]; }

    // ---- phase 1: local summary (a, bb) per n ----
    float a[16], bb[16];
    #pragma unroll
    for (int n = 0; n < 16; n++) {
        a[n] = __expf(sa * Acoef[n]);
        const float4* bp = (const float4*)(xB + (size_t)n * BL);
        float acc;
        #pragma unroll
        for (int i = 0; i < 4; i++) {
            float4 Bv = bp[i];
            if (i == 0) acc = du[0] * Bv.x;
            else        acc = fmaf(__expf(dv[i * 4] * Acoef[n]), acc, du[i * 4] * Bv.x);
            acc = fmaf(__expf(dv[i * 4 + 1] * Acoef[n]), acc, du[i * 4 + 1] * Bv.y);
            acc = fmaf(__expf(dv[i * 4 + 2] * Acoef[n]), acc, du[i * 4 + 2] * Bv.z);
            acc = fmaf(__expf(dv[i * 4 + 3] * Acoef[n]), acc, du[i * 4 + 3] * Bv.w);
        }
        bb[n] = acc;
    }

    // ---- ONE Kogge-Stone inclusive scan of affine maps over 64 lanes ----
    #pragma unroll
    for (int off = 1; off < 64; off <<= 1) {
        #pragma unroll
        for (int n = 0; n < 16; n++) {
            float pa = __shfl_up(a[n], off);
            float pb = __shfl_up(bb[n], off);
            if (lane >= off) {
                bb[n] = fmaf(a[n], pb, bb[n]);   // uses OLD a (newer ∘ older)
                a[n] *= pa;
            }
        }
    }

    // exclusive prefix -> h0 for this lane's 16 steps (global h0 = 0)
    float h[16];
    #pragma unroll
    for (int n = 0; n < 16; n++) {
        float pb = __shfl_up(bb[n], 1);
        h[n] = (lane == 0) ? 0.f : pb;
    }

    // ---- phase 2: rescan 16 steps + C-contraction ----
    float s[16];
    #pragma unroll
    for (int j = 0; j < 16; j++) s[j] = 0.f;
    #pragma unroll
    for (int n = 0; n < 16; n++) {
        const float4* bp = (const float4*)(xB + (size_t)n * BL);
        const float4* cp = (const float4*)(xC + (size_t)n * BL);
        float hn = h[n];
        #pragma unroll
        for (int i = 0; i < 4; i++) {
            float4 Bv = bp[i];
            float4 Cv = cp[i];
            hn = fmaf(__expf(dv[i * 4 + 0] * Acoef[n]), hn, du[i * 4 + 0] * Bv.x);
            s[i * 4 + 0] = fmaf(hn, Cv.x, s[i * 4 + 0]);
            hn = fmaf(__expf(dv[i * 4 + 1] * Acoef[n]), hn, du[i * 4 + 1] * Bv.y);
            s[i * 4 + 1] = fmaf(hn, Cv.y, s[i * 4 + 1]);
            hn = fmaf(__expf(dv[i * 4 + 2] * Acoef[n]), hn, du[i * 4 + 2] * Bv.z);
            s[i * 4 + 2] = fmaf(hn, Cv.z, s[i * 4 + 2]);
            hn = fmaf(__expf(dv[i * 4 + 3] * Acoef[n]), hn, du[i * 4 + 3] * Bv.w);
            s[i * 4 + 3] = fmaf(hn, Cv.w, s[i * 4 + 3]);
        }
    }

    // gate + store (lane-contiguous 64B lines)
    {
        const float4* zp = (const float4*)(xzT + row_z);
        float4* yp = (float4*)(yT + row_t);
        #pragma unroll
        for (int i = 0; i < 4; i++) {
            float4 zv = zp[i];
            float4 yv;
            float v0 = s[i * 4 + 0] + uv[i * 4 + 0] * Dd;
            float v1 = s[i * 4 + 1] + uv[i * 4 + 1] * Dd;
            float v2 = s[i * 4 + 2] + uv[i * 4 + 2] * Dd;
            float v3 = s[i * 4 + 3] + uv[i * 4 + 3] * Dd;
            yv.x = v0 * (zv.x / (1.f + __expf(-zv.x)));
            yv.y = v1 * (zv.y / (1.f + __expf(-zv.y)));
            yv.z = v2 * (zv.z / (1.f + __expf(-zv.z)));
            yv.w = v3 * (zv.w / (1.f + __expf(-zv.w)));
            yp[i] = yv;
        }
    }
}

// yT fp32 [DI][BL] -> yB bf16 [BL][DI], 64x64 LDS tiles.
__global__ __launch_bounds__(256) void transpose_cast(const float* __restrict__ yT,
        ushort* __restrict__ yB)
{
    __shared__ float t[64][65];
    const int bl0 = blockIdx.x * 64, d0 = blockIdx.y * 64;
    const int tid = threadIdx.x;
    #pragma unroll
    for (int i = 0; i < 4; i++) {
        int chunk = tid + i * 256;
        int dr = chunk >> 4, c4 = (chunk & 15) * 4;
        const float4 v = *(const float4*)&yT[(size_t)(d0 + dr) * BL + bl0 + c4];
        t[dr][c4 + 0] = v.x; t[dr][c4 + 1] = v.y;
        t[dr][c4 + 2] = v.z; t[dr][c4 + 3] = v.w;
    }
    __syncthreads();
    #pragma unroll
    for (int i = 0; i < 4; i++) {
        int chunk = tid + i * 256;
        int br = chunk >> 4, dc4 = (chunk & 15) * 4;
        ushort4 o;
        o.x = f2bf(t[dc4 + 0][br]); o.y = f2bf(t[dc4 + 1][br]);
        o.z = f2bf(t[dc4 + 2][br]); o.w = f2bf(t[dc4 + 3][br]);
        *(ushort4*)&yB[(size_t)(bl0 + br) * DI + d0 + dc4] = o;
    }
}

// LayerNorm over last dim (512), one block per row, fp32 out.
__global__ __launch_bounds__(256) void ln_kernel(const float* __restrict__ r,
        const float* __restrict__ lnw, const float* __restrict__ lnb,
        float* __restrict__ out)
{
    int row = blockIdx.x;
    const float* rr = r + (size_t)row * DM;
    float v0 = rr[threadIdx.x], v1 = rr[threadIdx.x + 256];
    float s = v0 + v1, s2 = v0 * v0 + v1 * v1;
    #pragma unroll
    for (int off = 32; off > 0; off >>= 1) {
        s  += __shfl_down(s, off);
        s2 += __shfl_down(s2, off);
    }
    __shared__ float ls[4], ls2[4];
    __shared__ float mu_s, rstd_s;
    int wid = threadIdx.x >> 6, lane = threadIdx.x & 63;
    if (lane == 0) { ls[wid] = s; ls2[wid] = s2; }
    __syncthreads();
    if (threadIdx.x == 0) {
        float S = ls[0] + ls[1] + ls[2] + ls[3];
        float S2 = ls2[0] + ls2[1] + ls2[2] + ls2[3];
        float mu = S * (1.f / DM);
        float var = S2 * (1.f / DM) - mu * mu;
        mu_s = mu;
        rstd_s = rsqrtf(var + 1e-5f);
    }
    __syncthreads();
    float mu = mu_s, rstd = rstd_s;
    out[(size_t)row * DM + threadIdx.x] =
        (v0 - mu) * rstd * lnw[threadIdx.x] + lnb[threadIdx.x];
    out[(size_t)row * DM + threadIdx.x + 256] =
        (v1 - mu) * rstd * lnw[threadIdx.x + 256] + lnb[threadIdx.x + 256];
}

extern "C" void kernel_launch(void* const* d_in, const int* in_sizes, int n_in,
                              void* d_out, int out_size, void* d_ws, size_t ws_size,
                              hipStream_t stream)
{
    const float* x         = (const float*)d_in[0];
    const float* in_proj_w = (const float*)d_in[1];
    const float* conv_w    = (const float*)d_in[2];
    const float* conv_b    = (const float*)d_in[3];
    const float* x_proj_w  = (const float*)d_in[4];
    const float* dt_proj_w = (const float*)d_in[5];
    const float* dt_proj_b = (const float*)d_in[6];
    const float* A_log     = (const float*)d_in[7];
    const float* Dvec      = (const float*)d_in[8];
    const float* out_proj_w= (const float*)d_in[9];
    const float* ln_w      = (const float*)d_in[10];
    const float* ln_b      = (const float*)d_in[11];
    float* out = (float*)d_out;

    // fp32 regions (floats)
    float* ws     = (float*)d_ws;
    float* xzT    = ws;                                  // 2048 x 4096 (32 MB)
    float* uT     = xzT    + (size_t)2048 * BL;          // 1024 x 4096 (16 MB)
    float* xdblT  = uT     + (size_t)DI * BL;            // 64 x 4096   (1 MB)
    float* yT     = xdblT  + (size_t)XDC * BL;           // 1024 x 4096 (16 MB)
    float* r      = yT     + (size_t)DI * BL;            // 4096 x 512  (8 MB)
    ushort* yB    = (ushort*)(r + (size_t)BL * DM);      // 4096 x 1024 bf16 (8 MB)
    float*  xdblp = yT;   // gemm3 partials (4 MB) alias yT: dead before scan writes yT

    dim3 blk(256);

    // 1) xzT[e][bl] = in_proj_w @ x^T : M=2048, N=4096, K=512 (MFMA, fp32 staged)
    gemm_mfma<0, true, true><<<dim3(BL / 128, 2048 / 128), blk, 0, stream>>>(
        in_proj_w, x, xzT, DM, BL, nullptr);

    // 2) uT = silu(causal_conv(xsT) + cb)
    conv_silu<<<(DI * BL / 4) / 256, blk, 0, stream>>>(xzT, conv_w, conv_b, uT);

    // 3) xdblT = (u @ x_proj_w^T)^T : transposed split-K partials + reduce
    gemm3_splitk<<<dim3(KS, BL / 32), blk, 0, stream>>>(uT, x_proj_w, xdblp);
    gemm3_reduce<<<(64 * BL / 4) / 256, blk, 0, stream>>>(xdblp, xdblT);

    // 4) fused scan: inline delta + scan + gate (single-chunk, wave-independent)
    scan_fused<<<B_ * DI / 4, blk, 0, stream>>>(
        uT, xdblT, xzT, A_log, Dvec, dt_proj_w, dt_proj_b, yT);

    // 5a) yT -> yB (bf16, [bl][d])
    transpose_cast<<<dim3(BL / 64, DI / 64), blk, 0, stream>>>(yT, yB);

    // 5b) r[bl][dm] = y @ out_proj_w^T + x : M=4096, N=512, K=1024 (MFMA, resid epi)
    gemm_mfma<2, false, true><<<dim3(DM / 128, BL / 128), blk, 0, stream>>>(
        yB, out_proj_w, r, DI, DM, x);

    // 6) LayerNorm -> fp32 out
    ln_kernel<<<BL, blk, 0, stream>>>(r, ln_w, ln_b, out);
}

// Round 12
// 267.138 us; speedup vs baseline: 1.1022x; 1.0472x over previous
//
#include <hip/hip_runtime.h>
#include <hip/hip_bf16.h>
#include <math.h>

// MambaBlock: B=4, L=1024, D_MODEL=512, D_INNER=1024, D_STATE=16, D_CONV=4, DT_RANK=32
// fp32 in/out. 9 dispatches (round-9 best configuration, 265.4 us):
//  gemm1 (MFMA, fp32-staged) -> conv_silu -> gemm3 splitk+reduce (TRANSPOSED out,
//  xdblT [64][BL], L2-resident) -> dt_softplus (coalesced gemv) ->
//  scan v8 (single-chunk: lane owns 16 contiguous steps; ONE Kogge-Stone pass;
//  no LDS, no barriers, no carry) -> transpose_cast -> gemm6 (MFMA) -> LN.
#define B_   4
#define L_   1024
#define DM   512
#define DI   1024
#define NS   16
#define XDC  64      // DT_RANK + 2*D_STATE
#define BL   4096    // B_*L_
#define KS   4       // gemm3 split-K factor

typedef short bfrag __attribute__((ext_vector_type(8)));   // 8 bf16
typedef float ffrag __attribute__((ext_vector_type(4)));   // 4 fp32 acc

__device__ __forceinline__ ushort f2bf(float v) {
    __hip_bfloat16 h = __float2bfloat16(v);
    return *(ushort*)&h;
}

// stage 8 elements (16B of bf16) into LDS; F32 => convert fp32 source in-register.
template<bool F32>
__device__ __forceinline__ void stage8(const void* p, size_t eoff, ushort* dst) {
    if constexpr (F32) {
        const float* f = (const float*)p + eoff;
        float4 v0 = *(const float4*)f;
        float4 v1 = *(const float4*)(f + 4);
        *(ushort4*)dst       = make_ushort4(f2bf(v0.x), f2bf(v0.y), f2bf(v0.z), f2bf(v0.w));
        *(ushort4*)(dst + 4) = make_ushort4(f2bf(v1.x), f2bf(v1.y), f2bf(v1.z), f2bf(v1.w));
    } else {
        *(uint4*)dst = *(const uint4*)((const ushort*)p + eoff);
    }
}

// MFMA bf16 TN GEMM: C[M,N] = A[M,K] * B[N,K]^T, fp32 out.
// 128x128 block tile, BK=32, 4 waves (2x2), wave tile 64x64 (4x4 of 16x16x32).
// AF/BF: operand source is fp32 (convert during staging) vs pre-cast bf16.
// EPI: 0 none; 2 C += resid[m*ldc+n]
template<int EPI, bool AF, bool BF>
__global__ __launch_bounds__(256) void gemm_mfma(const void* __restrict__ Ap,
        const void* __restrict__ Bp, float* __restrict__ C,
        int K, int ldc, const float* __restrict__ resid)
{
    __shared__ ushort As[128][40];
    __shared__ ushort Bs[128][40];
    const int tid = threadIdx.x;
    const int lane = tid & 63, wave = tid >> 6;
    const int wm = (wave & 1) * 64, wn = (wave >> 1) * 64;
    const int l15 = lane & 15, quad = lane >> 4;
    const int m0 = blockIdx.y * 128, n0 = blockIdx.x * 128;

    ffrag acc[4][4] = {};

    for (int k0 = 0; k0 < K; k0 += 32) {
        #pragma unroll
        for (int i = 0; i < 2; i++) {
            int chunk = tid + i * 256;
            int row = chunk >> 2, kk8 = (chunk & 3) * 8;
            stage8<AF>(Ap, (size_t)(m0 + row) * K + k0 + kk8, &As[row][kk8]);
            stage8<BF>(Bp, (size_t)(n0 + row) * K + k0 + kk8, &Bs[row][kk8]);
        }
        __syncthreads();
        bfrag af[4], bfv[4];
        #pragma unroll
        for (int i = 0; i < 4; i++) {
            af[i]  = *(const bfrag*)&As[wm + i * 16 + l15][quad * 8];
            bfv[i] = *(const bfrag*)&Bs[wn + i * 16 + l15][quad * 8];
        }
        #pragma unroll
        for (int i = 0; i < 4; i++)
            #pragma unroll
            for (int j = 0; j < 4; j++)
                acc[i][j] = __builtin_amdgcn_mfma_f32_16x16x32_bf16(af[i], bfv[j], acc[i][j], 0, 0, 0);
        __syncthreads();
    }

    #pragma unroll
    for (int i = 0; i < 4; i++) {
        #pragma unroll
        for (int j = 0; j < 4; j++) {
            int n = n0 + wn + j * 16 + l15;
            #pragma unroll
            for (int r = 0; r < 4; r++) {
                int m = m0 + wm + i * 16 + quad * 4 + r;
                float v = acc[i][j][r];
                if (EPI == 2) v += resid[(size_t)m * ldc + n];
                C[(size_t)m * ldc + n] = v;
            }
        }
    }
}

// gemm3 split-K, TRANSPOSED output: part[ks][n][m] = sum over K-chunk of u[m][k]*W[n][k].
// A = uT [K=DI][M=BL], W = x_proj_w [64][DI].
// Block: 32 m-rows x 64 n-cols, K-chunk = DI/KS = 256, BK=16.
// Thread t: owns n = t&63, m-range mg*8..mg*8+7 (mg = t>>6).
__global__ __launch_bounds__(256) void gemm3_splitk(const float* __restrict__ uT,
        const float* __restrict__ xw, float* __restrict__ part)
{
    __shared__ float As[16][33];    // [k][m] 32 m
    __shared__ float Ws[16][68];    // [k][n] 64 n
    const int tid = threadIdx.x;
    const int nn = tid & 63;
    const int mg = tid >> 6;        // 0..3
    const int ks = blockIdx.x, m0 = blockIdx.y * 32;
    const int kbase = ks * (DI / KS);
    float acc[8] = {};

    for (int k0 = 0; k0 < DI / KS; k0 += 16) {
        if (tid < 128) {
            int k = tid >> 3, m4 = (tid & 7) * 4;
            const float4 v = *(const float4*)&uT[(size_t)(kbase + k0 + k) * BL + m0 + m4];
            As[k][m4 + 0] = v.x; As[k][m4 + 1] = v.y;
            As[k][m4 + 2] = v.z; As[k][m4 + 3] = v.w;
        }
        {
            int r = tid >> 2, c4 = (tid & 3) * 4;
            const float4 v = *(const float4*)&xw[(size_t)r * DI + kbase + k0 + c4];
            Ws[c4 + 0][r] = v.x; Ws[c4 + 1][r] = v.y;
            Ws[c4 + 2][r] = v.z; Ws[c4 + 3][r] = v.w;
        }
        __syncthreads();
        #pragma unroll
        for (int kk = 0; kk < 16; kk++) {
            float w = Ws[kk][nn];
            #pragma unroll
            for (int i = 0; i < 8; i++)
                acc[i] = fmaf(As[kk][mg * 8 + i], w, acc[i]);
        }
        __syncthreads();
    }

    float* pp = part + (size_t)ks * 64 * BL + (size_t)nn * BL + m0 + mg * 8;
    *(float4*)&pp[0] = make_float4(acc[0], acc[1], acc[2], acc[3]);
    *(float4*)&pp[4] = make_float4(acc[4], acc[5], acc[6], acc[7]);
}

// reduce KS transposed partials -> xdblT [64][BL] fp32.
__global__ __launch_bounds__(256) void gemm3_reduce(const float* __restrict__ part,
        float* __restrict__ xdblT)
{
    int i = blockIdx.x * 256 + threadIdx.x;     // over 64*BL/4
    const float4* p0 = (const float4*)part;
    float4 a = p0[i];
    #pragma unroll
    for (int s = 1; s < KS; s++) {
        float4 b = p0[i + (size_t)s * 64 * BL / 4];
        a.x += b.x; a.y += b.y; a.z += b.z; a.w += b.w;
    }
    ((float4*)xdblT)[i] = a;
}

// delta[d][bl] = softplus(sum_k dtw[d][k] * xdblT[k][bl] + bias[d])
// Block: 4 waves; wave w owns d = blockIdx.y*4 + w. Thread owns one float4 of bl.
// All loads coalesced (row k of xdblT, 1KB per wave per k); xdblT is L2-resident.
__global__ __launch_bounds__(256) void dt_softplus(const float* __restrict__ xdblT,
        const float* __restrict__ dtw, const float* __restrict__ bias,
        float* __restrict__ deltaT)
{
    const int tid = threadIdx.x;
    const int lane = tid & 63;
    const int bl = blockIdx.x * 256 + lane * 4;

    int d = blockIdx.y * 4 + (tid >> 6);
    d = __builtin_amdgcn_readfirstlane(d);
    float wreg[32];
    {
        const float4* wp = (const float4*)(dtw + (size_t)d * 32);
        #pragma unroll
        for (int k = 0; k < 8; k++) *(float4*)&wreg[k * 4] = wp[k];
    }
    const float bb = bias[d];

    float4 acc = make_float4(bb, bb, bb, bb);
    #pragma unroll
    for (int k = 0; k < 32; k++) {
        float4 v = *(const float4*)&xdblT[(size_t)k * BL + bl];
        float w = wreg[k];
        acc.x = fmaf(w, v.x, acc.x);
        acc.y = fmaf(w, v.y, acc.y);
        acc.z = fmaf(w, v.z, acc.z);
        acc.w = fmaf(w, v.w, acc.w);
    }
    float4 o;
    o.x = (acc.x > 20.f) ? acc.x : __logf(1.f + __expf(acc.x));
    o.y = (acc.y > 20.f) ? acc.y : __logf(1.f + __expf(acc.y));
    o.z = (acc.z > 20.f) ? acc.z : __logf(1.f + __expf(acc.z));
    o.w = (acc.w > 20.f) ? acc.w : __logf(1.f + __expf(acc.w));
    *(float4*)&deltaT[(size_t)d * BL + bl] = o;
}

// depthwise causal conv (k=4) + bias + SiLU, channel-major, 4 outputs/thread.
__global__ __launch_bounds__(256) void conv_silu(const float* __restrict__ xzT,
        const float* __restrict__ cw, const float* __restrict__ cb,
        float* __restrict__ uT)
{
    int i = blockIdx.x * 256 + threadIdx.x;     // over DI*BL/4
    int d  = i >> 10;
    int q  = i & 1023;
    int bl = q * 4;
    int l  = bl & (L_ - 1);
    const float* row = xzT + (size_t)d * BL;
    float4 cur = *(const float4*)&row[bl];
    float4 prev = make_float4(0.f, 0.f, 0.f, 0.f);
    if (l != 0) prev = *(const float4*)&row[bl - 4];
    float v[7] = { prev.y, prev.z, prev.w, cur.x, cur.y, cur.z, cur.w };
    float w0 = cw[d * 4 + 0], w1 = cw[d * 4 + 1], w2 = cw[d * 4 + 2], w3 = cw[d * 4 + 3];
    float bias = cb[d];
    float4 o;
    o.x = bias + w0 * v[0] + w1 * v[1] + w2 * v[2] + w3 * v[3];
    o.y = bias + w0 * v[1] + w1 * v[2] + w2 * v[3] + w3 * v[4];
    o.z = bias + w0 * v[2] + w1 * v[3] + w2 * v[4] + w3 * v[5];
    o.w = bias + w0 * v[3] + w1 * v[4] + w2 * v[5] + w3 * v[6];
    o.x = o.x / (1.f + __expf(-o.x));
    o.y = o.y / (1.f + __expf(-o.y));
    o.z = o.z / (1.f + __expf(-o.z));
    o.w = o.w / (1.f + __expf(-o.w));
    *(float4*)&uT[(size_t)d * BL + bl] = o;
}

// ---- selective scan v8: single-chunk, barrier-free, LDS-free ----
// Block = 4 waves = 4 (b,d); wave owns one (b,d). Lane k owns timesteps
// [16k, 16k+16) (64 lanes x 16 = L); all 16 n-states live in registers.
//  - B/C read DIRECTLY from xdblT rows (32+n / 48+n): lane reads its own 64B
//    line; wave covers 4KB contiguous -> line-coalesced, L2-resident (1 MB)
//  - phase 1: 16-step local affine summary (a = exp(Acoef*sum_dv), bb = h_end|0)
//  - ONE Kogge-Stone shfl scan over 64 lanes (6 rounds); h0 = exclusive prefix
//  - phase 2: 16-step rescan + local C-contraction; gate; store
//  - no inter-chunk carry, no __syncthreads, no LDS.
__global__ __launch_bounds__(256) void scan_fused(const float* __restrict__ deltaT,
        const float* __restrict__ uT, const float* __restrict__ xdblT,
        const float* __restrict__ xzT, const float* __restrict__ A_log,
        const float* __restrict__ Dp, float* __restrict__ yT)
{
    const int tid = threadIdx.x;
    const int lane = tid & 63;
    const int bd = blockIdx.x * 4 + (tid >> 6);
    const int d = bd & (DI - 1);
    const int b = bd >> 10;

    float Acoef[16];
    {
        const float4* ap = (const float4*)(A_log + d * NS);
        #pragma unroll
        for (int i = 0; i < 4; i++) {
            float4 v = ap[i];
            Acoef[i * 4 + 0] = -__expf(v.x); Acoef[i * 4 + 1] = -__expf(v.y);
            Acoef[i * 4 + 2] = -__expf(v.z); Acoef[i * 4 + 3] = -__expf(v.w);
        }
    }
    const float Dd = Dp[d];

    const size_t row_t = (size_t)d * BL + b * L_ + lane * 16;
    const size_t row_z = (size_t)(DI + d) * BL + b * L_ + lane * 16;
    const float* xB = xdblT + (size_t)32 * BL + b * L_ + lane * 16;  // B row n: +n*BL
    const float* xC = xdblT + (size_t)48 * BL + b * L_ + lane * 16;  // C row n: +n*BL

    // load 16 steps of delta, u (lane-contiguous 64B lines)
    float dv[16], uv[16];
    {
        const float4* dp = (const float4*)(deltaT + row_t);
        const float4* up = (const float4*)(uT + row_t);
        #pragma unroll
        for (int i = 0; i < 4; i++) {
            *(float4*)&dv[i * 4] = dp[i];
            *(float4*)&uv[i * 4] = up[i];
        }
    }
    float du[16];
    float sa = 0.f;
    #pragma unroll
    for (int j = 0; j < 16; j++) { du[j] = dv[j] * uv[j]; sa += dv[j]; }

    // ---- phase 1: local summary (a, bb) per n ----
    float a[16], bb[16];
    #pragma unroll
    for (int n = 0; n < 16; n++) {
        a[n] = __expf(sa * Acoef[n]);
        const float4* bp = (const float4*)(xB + (size_t)n * BL);
        float acc;
        #pragma unroll
        for (int i = 0; i < 4; i++) {
            float4 Bv = bp[i];
            if (i == 0) acc = du[0] * Bv.x;
            else        acc = fmaf(__expf(dv[i * 4] * Acoef[n]), acc, du[i * 4] * Bv.x);
            acc = fmaf(__expf(dv[i * 4 + 1] * Acoef[n]), acc, du[i * 4 + 1] * Bv.y);
            acc = fmaf(__expf(dv[i * 4 + 2] * Acoef[n]), acc, du[i * 4 + 2] * Bv.z);
            acc = fmaf(__expf(dv[i * 4 + 3] * Acoef[n]), acc, du[i * 4 + 3] * Bv.w);
        }
        bb[n] = acc;
    }

    // ---- ONE Kogge-Stone inclusive scan of affine maps over 64 lanes ----
    #pragma unroll
    for (int off = 1; off < 64; off <<= 1) {
        #pragma unroll
        for (int n = 0; n < 16; n++) {
            float pa = __shfl_up(a[n], off);
            float pb = __shfl_up(bb[n], off);
            if (lane >= off) {
                bb[n] = fmaf(a[n], pb, bb[n]);   // uses OLD a (newer ∘ older)
                a[n] *= pa;
            }
        }
    }

    // exclusive prefix -> h0 for this lane's 16 steps (global h0 = 0)
    float h[16];
    #pragma unroll
    for (int n = 0; n < 16; n++) {
        float pb = __shfl_up(bb[n], 1);
        h[n] = (lane == 0) ? 0.f : pb;
    }

    // ---- phase 2: rescan 16 steps + C-contraction ----
    float s[16];
    #pragma unroll
    for (int j = 0; j < 16; j++) s[j] = 0.f;
    #pragma unroll
    for (int n = 0; n < 16; n++) {
        const float4* bp = (const float4*)(xB + (size_t)n * BL);
        const float4* cp = (const float4*)(xC + (size_t)n * BL);
        float hn = h[n];
        #pragma unroll
        for (int i = 0; i < 4; i++) {
            float4 Bv = bp[i];
            float4 Cv = cp[i];
            hn = fmaf(__expf(dv[i * 4 + 0] * Acoef[n]), hn, du[i * 4 + 0] * Bv.x);
            s[i * 4 + 0] = fmaf(hn, Cv.x, s[i * 4 + 0]);
            hn = fmaf(__expf(dv[i * 4 + 1] * Acoef[n]), hn, du[i * 4 + 1] * Bv.y);
            s[i * 4 + 1] = fmaf(hn, Cv.y, s[i * 4 + 1]);
            hn = fmaf(__expf(dv[i * 4 + 2] * Acoef[n]), hn, du[i * 4 + 2] * Bv.z);
            s[i * 4 + 2] = fmaf(hn, Cv.z, s[i * 4 + 2]);
            hn = fmaf(__expf(dv[i * 4 + 3] * Acoef[n]), hn, du[i * 4 + 3] * Bv.w);
            s[i * 4 + 3] = fmaf(hn, Cv.w, s[i * 4 + 3]);
        }
    }

    // gate + store (lane-contiguous 64B lines)
    {
        const float4* zp = (const float4*)(xzT + row_z);
        float4* yp = (float4*)(yT + row_t);
        #pragma unroll
        for (int i = 0; i < 4; i++) {
            float4 zv = zp[i];
            float4 yv;
            float v0 = s[i * 4 + 0] + uv[i * 4 + 0] * Dd;
            float v1 = s[i * 4 + 1] + uv[i * 4 + 1] * Dd;
            float v2 = s[i * 4 + 2] + uv[i * 4 + 2] * Dd;
            float v3 = s[i * 4 + 3] + uv[i * 4 + 3] * Dd;
            yv.x = v0 * (zv.x / (1.f + __expf(-zv.x)));
            yv.y = v1 * (zv.y / (1.f + __expf(-zv.y)));
            yv.z = v2 * (zv.z / (1.f + __expf(-zv.z)));
            yv.w = v3 * (zv.w / (1.f + __expf(-zv.w)));
            yp[i] = yv;
        }
    }
}

// yT fp32 [DI][BL] -> yB bf16 [BL][DI], 64x64 LDS tiles.
__global__ __launch_bounds__(256) void transpose_cast(const float* __restrict__ yT,
        ushort* __restrict__ yB)
{
    __shared__ float t[64][65];
    const int bl0 = blockIdx.x * 64, d0 = blockIdx.y * 64;
    const int tid = threadIdx.x;
    #pragma unroll
    for (int i = 0; i < 4; i++) {
        int chunk = tid + i * 256;
        int dr = chunk >> 4, c4 = (chunk & 15) * 4;
        const float4 v = *(const float4*)&yT[(size_t)(d0 + dr) * BL + bl0 + c4];
        t[dr][c4 + 0] = v.x; t[dr][c4 + 1] = v.y;
        t[dr][c4 + 2] = v.z; t[dr][c4 + 3] = v.w;
    }
    __syncthreads();
    #pragma unroll
    for (int i = 0; i < 4; i++) {
        int chunk = tid + i * 256;
        int br = chunk >> 4, dc4 = (chunk & 15) * 4;
        ushort4 o;
        o.x = f2bf(t[dc4 + 0][br]); o.y = f2bf(t[dc4 + 1][br]);
        o.z = f2bf(t[dc4 + 2][br]); o.w = f2bf(t[dc4 + 3][br]);
        *(ushort4*)&yB[(size_t)(bl0 + br) * DI + d0 + dc4] = o;
    }
}

// LayerNorm over last dim (512), one block per row, fp32 out.
__global__ __launch_bounds__(256) void ln_kernel(const float* __restrict__ r,
        const float* __restrict__ lnw, const float* __restrict__ lnb,
        float* __restrict__ out)
{
    int row = blockIdx.x;
    const float* rr = r + (size_t)row * DM;
    float v0 = rr[threadIdx.x], v1 = rr[threadIdx.x + 256];
    float s = v0 + v1, s2 = v0 * v0 + v1 * v1;
    #pragma unroll
    for (int off = 32; off > 0; off >>= 1) {
        s  += __shfl_down(s, off);
        s2 += __shfl_down(s2, off);
    }
    __shared__ float ls[4], ls2[4];
    __shared__ float mu_s, rstd_s;
    int wid = threadIdx.x >> 6, lane = threadIdx.x & 63;
    if (lane == 0) { ls[wid] = s; ls2[wid] = s2; }
    __syncthreads();
    if (threadIdx.x == 0) {
        float S = ls[0] + ls[1] + ls[2] + ls[3];
        float S2 = ls2[0] + ls2[1] + ls2[2] + ls2[3];
        float mu = S * (1.f / DM);
        float var = S2 * (1.f / DM) - mu * mu;
        mu_s = mu;
        rstd_s = rsqrtf(var + 1e-5f);
    }
    __syncthreads();
    float mu = mu_s, rstd = rstd_s;
    out[(size_t)row * DM + threadIdx.x] =
        (v0 - mu) * rstd * lnw[threadIdx.x] + lnb[threadIdx.x];
    out[(size_t)row * DM + threadIdx.x + 256] =
        (v1 - mu) * rstd * lnw[threadIdx.x + 256] + lnb[threadIdx.x + 256];
}

extern "C" void kernel_launch(void* const* d_in, const int* in_sizes, int n_in,
                              void* d_out, int out_size, void* d_ws, size_t ws_size,
                              hipStream_t stream)
{
    const float* x         = (const float*)d_in[0];
    const float* in_proj_w = (const float*)d_in[1];
    const float* conv_w    = (const float*)d_in[2];
    const float* conv_b    = (const float*)d_in[3];
    const float* x_proj_w  = (const float*)d_in[4];
    const float* dt_proj_w = (const float*)d_in[5];
    const float* dt_proj_b = (const float*)d_in[6];
    const float* A_log     = (const float*)d_in[7];
    const float* Dvec      = (const float*)d_in[8];
    const float* out_proj_w= (const float*)d_in[9];
    const float* ln_w      = (const float*)d_in[10];
    const float* ln_b      = (const float*)d_in[11];
    float* out = (float*)d_out;

    // fp32 regions (floats)
    float* ws     = (float*)d_ws;
    float* xzT    = ws;                                  // 2048 x 4096 (32 MB)
    float* uT     = xzT    + (size_t)2048 * BL;          // 1024 x 4096 (16 MB)
    float* xdblT  = uT     + (size_t)DI * BL;            // 64 x 4096   (1 MB)
    float* deltaT = xdblT  + (size_t)XDC * BL;           // 1024 x 4096 (16 MB)
    float* yT     = deltaT + (size_t)DI * BL;            // 1024 x 4096 (16 MB)
    float* r      = yT     + (size_t)DI * BL;            // 4096 x 512  (8 MB)
    // aliases over time-dead regions:
    float*  xdblp = yT;                                  // KS*64*BL fl = 4 MB, gemm3 partials
    ushort* yB    = (ushort*)deltaT;                     // deltaT dead after scan

    dim3 blk(256);

    // 1) xzT[e][bl] = in_proj_w @ x^T : M=2048, N=4096, K=512 (MFMA, fp32 staged)
    gemm_mfma<0, true, true><<<dim3(BL / 128, 2048 / 128), blk, 0, stream>>>(
        in_proj_w, x, xzT, DM, BL, nullptr);

    // 2) uT = silu(causal_conv(xsT) + cb)
    conv_silu<<<(DI * BL / 4) / 256, blk, 0, stream>>>(xzT, conv_w, conv_b, uT);

    // 3) xdblT = (u @ x_proj_w^T)^T : transposed split-K partials + reduce
    gemm3_splitk<<<dim3(KS, BL / 32), blk, 0, stream>>>(uT, x_proj_w, xdblp);
    gemm3_reduce<<<(64 * BL / 4) / 256, blk, 0, stream>>>(xdblp, xdblT);

    // 4) deltaT[d][bl] = softplus(dtw[d] . xdblT[0:32][bl] + b) : coalesced gemv
    dt_softplus<<<dim3(BL / 256, DI / 4), blk, 0, stream>>>(
        xdblT, dt_proj_w, dt_proj_b, deltaT);

    // 5) fused selective scan + gate (single-chunk, wave-independent)
    scan_fused<<<B_ * DI / 4, blk, 0, stream>>>(
        deltaT, uT, xdblT, xzT, A_log, Dvec, yT);

    // 6a) yT -> yB (bf16, [bl][d])
    transpose_cast<<<dim3(BL / 64, DI / 64), blk, 0, stream>>>(yT, yB);

    // 6b) r[bl][dm] = y @ out_proj_w^T + x : M=4096, N=512, K=1024 (MFMA, resid epi)
    gemm_mfma<2, false, true><<<dim3(DM / 128, BL / 128), blk, 0, stream>>>(
        yB, out_proj_w, r, DI, DM, x);

    // 7) LayerNorm -> fp32 out
    ln_kernel<<<BL, blk, 0, stream>>>(r, ln_w, ln_b, out);
}

// Round 13
// 255.085 us; speedup vs baseline: 1.1543x; 1.0472x over previous
//
#include <hip/hip_runtime.h>
#include <hip/hip_bf16.h>
#include <math.h>

// MambaBlock: B=4, L=1024, D_MODEL=512, D_INNER=1024, D_STATE=16, D_CONV=4, DT_RANK=32
// fp32 in/out. 9 dispatches:
//  gemm1 (MFMA 128x128, fp32-staged) -> conv_silu -> gemm3 splitk (b128 LDS) +
//  reduce (TRANSPOSED out, xdblT [64][BL], L2-resident) -> dt_softplus ->
//  scan v8 (single-chunk, lane owns 16 steps, ONE Kogge-Stone, no LDS/barriers)
//  -> transpose_cast -> gemm6 (MFMA 128x64 tile: 256 blocks = 1/CU) -> LN.
#define B_   4
#define L_   1024
#define DM   512
#define DI   1024
#define NS   16
#define XDC  64      // DT_RANK + 2*D_STATE
#define BL   4096    // B_*L_
#define KS   4       // gemm3 split-K factor

typedef short bfrag __attribute__((ext_vector_type(8)));   // 8 bf16
typedef float ffrag __attribute__((ext_vector_type(4)));   // 4 fp32 acc

__device__ __forceinline__ ushort f2bf(float v) {
    __hip_bfloat16 h = __float2bfloat16(v);
    return *(ushort*)&h;
}

// stage 8 elements (16B of bf16) into LDS; F32 => convert fp32 source in-register.
template<bool F32>
__device__ __forceinline__ void stage8(const void* p, size_t eoff, ushort* dst) {
    if constexpr (F32) {
        const float* f = (const float*)p + eoff;
        float4 v0 = *(const float4*)f;
        float4 v1 = *(const float4*)(f + 4);
        *(ushort4*)dst       = make_ushort4(f2bf(v0.x), f2bf(v0.y), f2bf(v0.z), f2bf(v0.w));
        *(ushort4*)(dst + 4) = make_ushort4(f2bf(v1.x), f2bf(v1.y), f2bf(v1.z), f2bf(v1.w));
    } else {
        *(uint4*)dst = *(const uint4*)((const ushort*)p + eoff);
    }
}

// MFMA bf16 TN GEMM: C[M,N] = A[M,K] * B[N,K]^T, fp32 out.
// 128x128 block tile, BK=32, 4 waves (2x2), wave tile 64x64 (4x4 of 16x16x32).
// AF/BF: operand source is fp32 (convert during staging) vs pre-cast bf16.
// EPI: 0 none; 2 C += resid[m*ldc+n]
template<int EPI, bool AF, bool BF>
__global__ __launch_bounds__(256) void gemm_mfma(const void* __restrict__ Ap,
        const void* __restrict__ Bp, float* __restrict__ C,
        int K, int ldc, const float* __restrict__ resid)
{
    __shared__ ushort As[128][40];
    __shared__ ushort Bs[128][40];
    const int tid = threadIdx.x;
    const int lane = tid & 63, wave = tid >> 6;
    const int wm = (wave & 1) * 64, wn = (wave >> 1) * 64;
    const int l15 = lane & 15, quad = lane >> 4;
    const int m0 = blockIdx.y * 128, n0 = blockIdx.x * 128;

    ffrag acc[4][4] = {};

    for (int k0 = 0; k0 < K; k0 += 32) {
        #pragma unroll
        for (int i = 0; i < 2; i++) {
            int chunk = tid + i * 256;
            int row = chunk >> 2, kk8 = (chunk & 3) * 8;
            stage8<AF>(Ap, (size_t)(m0 + row) * K + k0 + kk8, &As[row][kk8]);
            stage8<BF>(Bp, (size_t)(n0 + row) * K + k0 + kk8, &Bs[row][kk8]);
        }
        __syncthreads();
        bfrag af[4], bfv[4];
        #pragma unroll
        for (int i = 0; i < 4; i++) {
            af[i]  = *(const bfrag*)&As[wm + i * 16 + l15][quad * 8];
            bfv[i] = *(const bfrag*)&Bs[wn + i * 16 + l15][quad * 8];
        }
        #pragma unroll
        for (int i = 0; i < 4; i++)
            #pragma unroll
            for (int j = 0; j < 4; j++)
                acc[i][j] = __builtin_amdgcn_mfma_f32_16x16x32_bf16(af[i], bfv[j], acc[i][j], 0, 0, 0);
        __syncthreads();
    }

    #pragma unroll
    for (int i = 0; i < 4; i++) {
        #pragma unroll
        for (int j = 0; j < 4; j++) {
            int n = n0 + wn + j * 16 + l15;
            #pragma unroll
            for (int r = 0; r < 4; r++) {
                int m = m0 + wm + i * 16 + quad * 4 + r;
                float v = acc[i][j][r];
                if (EPI == 2) v += resid[(size_t)m * ldc + n];
                C[(size_t)m * ldc + n] = v;
            }
        }
    }
}

// MFMA bf16 TN GEMM, 128x64 tile (for N=512 outputs: grid 8x32 = 256 blocks =
// 1 per CU; the 128x128 tile left half the machine idle at N=512).
// 4 waves 2x2, wave tile 64x32 (4x2 of 16x16x32). EPI=2: C += resid.
template<int EPI, bool AF, bool BF>
__global__ __launch_bounds__(256) void gemm_mfma_n64(const void* __restrict__ Ap,
        const void* __restrict__ Bp, float* __restrict__ C,
        int K, int ldc, const float* __restrict__ resid)
{
    __shared__ ushort As[128][40];
    __shared__ ushort Bs[64][40];
    const int tid = threadIdx.x;
    const int lane = tid & 63, wave = tid >> 6;
    const int wm = (wave & 1) * 64, wn = (wave >> 1) * 32;
    const int l15 = lane & 15, quad = lane >> 4;
    const int m0 = blockIdx.y * 128, n0 = blockIdx.x * 64;

    ffrag acc[4][2] = {};

    for (int k0 = 0; k0 < K; k0 += 32) {
        #pragma unroll
        for (int i = 0; i < 2; i++) {
            int chunk = tid + i * 256;
            int row = chunk >> 2, kk8 = (chunk & 3) * 8;
            stage8<AF>(Ap, (size_t)(m0 + row) * K + k0 + kk8, &As[row][kk8]);
        }
        {
            int row = tid >> 2, kk8 = (tid & 3) * 8;
            stage8<BF>(Bp, (size_t)(n0 + row) * K + k0 + kk8, &Bs[row][kk8]);
        }
        __syncthreads();
        bfrag af[4], bfv[2];
        #pragma unroll
        for (int i = 0; i < 4; i++)
            af[i] = *(const bfrag*)&As[wm + i * 16 + l15][quad * 8];
        #pragma unroll
        for (int j = 0; j < 2; j++)
            bfv[j] = *(const bfrag*)&Bs[wn + j * 16 + l15][quad * 8];
        #pragma unroll
        for (int i = 0; i < 4; i++)
            #pragma unroll
            for (int j = 0; j < 2; j++)
                acc[i][j] = __builtin_amdgcn_mfma_f32_16x16x32_bf16(af[i], bfv[j], acc[i][j], 0, 0, 0);
        __syncthreads();
    }

    #pragma unroll
    for (int i = 0; i < 4; i++) {
        #pragma unroll
        for (int j = 0; j < 2; j++) {
            int n = n0 + wn + j * 16 + l15;
            #pragma unroll
            for (int r = 0; r < 4; r++) {
                int m = m0 + wm + i * 16 + quad * 4 + r;
                float v = acc[i][j][r];
                if (EPI == 2) v += resid[(size_t)m * ldc + n];
                C[(size_t)m * ldc + n] = v;
            }
        }
    }
}

// gemm3 split-K, TRANSPOSED output: part[ks][n][m] = sum over K-chunk of u[m][k]*W[n][k].
// A = uT [K=DI][M=BL], W = x_proj_w [64][DI].
// Block: 32 m-rows x 64 n-cols, K-chunk = DI/KS = 256, BK=16.
// As stride 36 floats (144B, 16B-aligned rows) so the wave-uniform A reads are
// 2x ds_read_b128 (was 8x scalar b32): inner loop 3 LDS reads + 8 fma.
__global__ __launch_bounds__(256) void gemm3_splitk(const float* __restrict__ uT,
        const float* __restrict__ xw, float* __restrict__ part)
{
    __shared__ float As[16][36];    // [k][m] 32 m, 16B-aligned rows
    __shared__ float Ws[16][68];    // [k][n] 64 n
    const int tid = threadIdx.x;
    const int nn = tid & 63;
    const int mg = tid >> 6;        // 0..3
    const int ks = blockIdx.x, m0 = blockIdx.y * 32;
    const int kbase = ks * (DI / KS);
    float acc[8] = {};

    for (int k0 = 0; k0 < DI / KS; k0 += 16) {
        if (tid < 128) {
            int k = tid >> 3, m4 = (tid & 7) * 4;
            const float4 v = *(const float4*)&uT[(size_t)(kbase + k0 + k) * BL + m0 + m4];
            *(float4*)&As[k][m4] = v;
        }
        {
            int r = tid >> 2, c4 = (tid & 3) * 4;
            const float4 v = *(const float4*)&xw[(size_t)r * DI + kbase + k0 + c4];
            Ws[c4 + 0][r] = v.x; Ws[c4 + 1][r] = v.y;
            Ws[c4 + 2][r] = v.z; Ws[c4 + 3][r] = v.w;
        }
        __syncthreads();
        #pragma unroll
        for (int kk = 0; kk < 16; kk++) {
            float w = Ws[kk][nn];
            float4 a0 = *(const float4*)&As[kk][mg * 8];
            float4 a1 = *(const float4*)&As[kk][mg * 8 + 4];
            acc[0] = fmaf(a0.x, w, acc[0]);
            acc[1] = fmaf(a0.y, w, acc[1]);
            acc[2] = fmaf(a0.z, w, acc[2]);
            acc[3] = fmaf(a0.w, w, acc[3]);
            acc[4] = fmaf(a1.x, w, acc[4]);
            acc[5] = fmaf(a1.y, w, acc[5]);
            acc[6] = fmaf(a1.z, w, acc[6]);
            acc[7] = fmaf(a1.w, w, acc[7]);
        }
        __syncthreads();
    }

    float* pp = part + (size_t)ks * 64 * BL + (size_t)nn * BL + m0 + mg * 8;
    *(float4*)&pp[0] = make_float4(acc[0], acc[1], acc[2], acc[3]);
    *(float4*)&pp[4] = make_float4(acc[4], acc[5], acc[6], acc[7]);
}

// reduce KS transposed partials -> xdblT [64][BL] fp32.
__global__ __launch_bounds__(256) void gemm3_reduce(const float* __restrict__ part,
        float* __restrict__ xdblT)
{
    int i = blockIdx.x * 256 + threadIdx.x;     // over 64*BL/4
    const float4* p0 = (const float4*)part;
    float4 a = p0[i];
    #pragma unroll
    for (int s = 1; s < KS; s++) {
        float4 b = p0[i + (size_t)s * 64 * BL / 4];
        a.x += b.x; a.y += b.y; a.z += b.z; a.w += b.w;
    }
    ((float4*)xdblT)[i] = a;
}

// delta[d][bl] = softplus(sum_k dtw[d][k] * xdblT[k][bl] + bias[d])
// Block: 4 waves; wave w owns d = blockIdx.y*4 + w. Thread owns one float4 of bl.
// All loads coalesced (row k of xdblT, 1KB per wave per k); xdblT is L2-resident.
__global__ __launch_bounds__(256) void dt_softplus(const float* __restrict__ xdblT,
        const float* __restrict__ dtw, const float* __restrict__ bias,
        float* __restrict__ deltaT)
{
    const int tid = threadIdx.x;
    const int lane = tid & 63;
    const int bl = blockIdx.x * 256 + lane * 4;

    int d = blockIdx.y * 4 + (tid >> 6);
    d = __builtin_amdgcn_readfirstlane(d);
    float wreg[32];
    {
        const float4* wp = (const float4*)(dtw + (size_t)d * 32);
        #pragma unroll
        for (int k = 0; k < 8; k++) *(float4*)&wreg[k * 4] = wp[k];
    }
    const float bb = bias[d];

    float4 acc = make_float4(bb, bb, bb, bb);
    #pragma unroll
    for (int k = 0; k < 32; k++) {
        float4 v = *(const float4*)&xdblT[(size_t)k * BL + bl];
        float w = wreg[k];
        acc.x = fmaf(w, v.x, acc.x);
        acc.y = fmaf(w, v.y, acc.y);
        acc.z = fmaf(w, v.z, acc.z);
        acc.w = fmaf(w, v.w, acc.w);
    }
    float4 o;
    o.x = (acc.x > 20.f) ? acc.x : __logf(1.f + __expf(acc.x));
    o.y = (acc.y > 20.f) ? acc.y : __logf(1.f + __expf(acc.y));
    o.z = (acc.z > 20.f) ? acc.z : __logf(1.f + __expf(acc.z));
    o.w = (acc.w > 20.f) ? acc.w : __logf(1.f + __expf(acc.w));
    *(float4*)&deltaT[(size_t)d * BL + bl] = o;
}

// depthwise causal conv (k=4) + bias + SiLU, channel-major, 4 outputs/thread.
__global__ __launch_bounds__(256) void conv_silu(const float* __restrict__ xzT,
        const float* __restrict__ cw, const float* __restrict__ cb,
        float* __restrict__ uT)
{
    int i = blockIdx.x * 256 + threadIdx.x;     // over DI*BL/4
    int d  = i >> 10;
    int q  = i & 1023;
    int bl = q * 4;
    int l  = bl & (L_ - 1);
    const float* row = xzT + (size_t)d * BL;
    float4 cur = *(const float4*)&row[bl];
    float4 prev = make_float4(0.f, 0.f, 0.f, 0.f);
    if (l != 0) prev = *(const float4*)&row[bl - 4];
    float v[7] = { prev.y, prev.z, prev.w, cur.x, cur.y, cur.z, cur.w };
    float w0 = cw[d * 4 + 0], w1 = cw[d * 4 + 1], w2 = cw[d * 4 + 2], w3 = cw[d * 4 + 3];
    float bias = cb[d];
    float4 o;
    o.x = bias + w0 * v[0] + w1 * v[1] + w2 * v[2] + w3 * v[3];
    o.y = bias + w0 * v[1] + w1 * v[2] + w2 * v[3] + w3 * v[4];
    o.z = bias + w0 * v[2] + w1 * v[3] + w2 * v[4] + w3 * v[5];
    o.w = bias + w0 * v[3] + w1 * v[4] + w2 * v[5] + w3 * v[6];
    o.x = o.x / (1.f + __expf(-o.x));
    o.y = o.y / (1.f + __expf(-o.y));
    o.z = o.z / (1.f + __expf(-o.z));
    o.w = o.w / (1.f + __expf(-o.w));
    *(float4*)&uT[(size_t)d * BL + bl] = o;
}

// ---- selective scan v8: single-chunk, barrier-free, LDS-free ----
// Block = 4 waves = 4 (b,d); wave owns one (b,d). Lane k owns timesteps
// [16k, 16k+16) (64 lanes x 16 = L); all 16 n-states live in registers.
//  - B/C read DIRECTLY from xdblT rows (32+n / 48+n): lane reads its own 64B
//    line; wave covers 4KB contiguous -> line-coalesced, L2-resident (1 MB)
//  - phase 1: 16-step local affine summary (a = exp(Acoef*sum_dv), bb = h_end|0)
//  - ONE Kogge-Stone shfl scan over 64 lanes (6 rounds); h0 = exclusive prefix
//  - phase 2: 16-step rescan + local C-contraction; gate; store
//  - no inter-chunk carry, no __syncthreads, no LDS.
__global__ __launch_bounds__(256) void scan_fused(const float* __restrict__ deltaT,
        const float* __restrict__ uT, const float* __restrict__ xdblT,
        const float* __restrict__ xzT, const float* __restrict__ A_log,
        const float* __restrict__ Dp, float* __restrict__ yT)
{
    const int tid = threadIdx.x;
    const int lane = tid & 63;
    const int bd = blockIdx.x * 4 + (tid >> 6);
    const int d = bd & (DI - 1);
    const int b = bd >> 10;

    float Acoef[16];
    {
        const float4* ap = (const float4*)(A_log + d * NS);
        #pragma unroll
        for (int i = 0; i < 4; i++) {
            float4 v = ap[i];
            Acoef[i * 4 + 0] = -__expf(v.x); Acoef[i * 4 + 1] = -__expf(v.y);
            Acoef[i * 4 + 2] = -__expf(v.z); Acoef[i * 4 + 3] = -__expf(v.w);
        }
    }
    const float Dd = Dp[d];

    const size_t row_t = (size_t)d * BL + b * L_ + lane * 16;
    const size_t row_z = (size_t)(DI + d) * BL + b * L_ + lane * 16;
    const float* xB = xdblT + (size_t)32 * BL + b * L_ + lane * 16;  // B row n: +n*BL
    const float* xC = xdblT + (size_t)48 * BL + b * L_ + lane * 16;  // C row n: +n*BL

    // load 16 steps of delta, u (lane-contiguous 64B lines)
    float dv[16], uv[16];
    {
        const float4* dp = (const float4*)(deltaT + row_t);
        const float4* up = (const float4*)(uT + row_t);
        #pragma unroll
        for (int i = 0; i < 4; i++) {
            *(float4*)&dv[i * 4] = dp[i];
            *(float4*)&uv[i * 4] = up[i];
        }
    }
    float du[16];
    float sa = 0.f;
    #pragma unroll
    for (int j = 0; j < 16; j++) { du[j] = dv[j] * uv[j]; sa += dv[j]; }

    // ---- phase 1: local summary (a, bb) per n ----
    float a[16], bb[16];
    #pragma unroll
    for (int n = 0; n < 16; n++) {
        a[n] = __expf(sa * Acoef[n]);
        const float4* bp = (const float4*)(xB + (size_t)n * BL);
        float acc;
        #pragma unroll
        for (int i = 0; i < 4; i++) {
            float4 Bv = bp[i];
            if (i == 0) acc = du[0] * Bv.x;
            else        acc = fmaf(__expf(dv[i * 4] * Acoef[n]), acc, du[i * 4] * Bv.x);
            acc = fmaf(__expf(dv[i * 4 + 1] * Acoef[n]), acc, du[i * 4 + 1] * Bv.y);
            acc = fmaf(__expf(dv[i * 4 + 2] * Acoef[n]), acc, du[i * 4 + 2] * Bv.z);
            acc = fmaf(__expf(dv[i * 4 + 3] * Acoef[n]), acc, du[i * 4 + 3] * Bv.w);
        }
        bb[n] = acc;
    }

    // ---- ONE Kogge-Stone inclusive scan of affine maps over 64 lanes ----
    #pragma unroll
    for (int off = 1; off < 64; off <<= 1) {
        #pragma unroll
        for (int n = 0; n < 16; n++) {
            float pa = __shfl_up(a[n], off);
            float pb = __shfl_up(bb[n], off);
            if (lane >= off) {
                bb[n] = fmaf(a[n], pb, bb[n]);   // uses OLD a (newer ∘ older)
                a[n] *= pa;
            }
        }
    }

    // exclusive prefix -> h0 for this lane's 16 steps (global h0 = 0)
    float h[16];
    #pragma unroll
    for (int n = 0; n < 16; n++) {
        float pb = __shfl_up(bb[n], 1);
        h[n] = (lane == 0) ? 0.f : pb;
    }

    // ---- phase 2: rescan 16 steps + C-contraction ----
    float s[16];
    #pragma unroll
    for (int j = 0; j < 16; j++) s[j] = 0.f;
    #pragma unroll
    for (int n = 0; n < 16; n++) {
        const float4* bp = (const float4*)(xB + (size_t)n * BL);
        const float4* cp = (const float4*)(xC + (size_t)n * BL);
        float hn = h[n];
        #pragma unroll
        for (int i = 0; i < 4; i++) {
            float4 Bv = bp[i];
            float4 Cv = cp[i];
            hn = fmaf(__expf(dv[i * 4 + 0] * Acoef[n]), hn, du[i * 4 + 0] * Bv.x);
            s[i * 4 + 0] = fmaf(hn, Cv.x, s[i * 4 + 0]);
            hn = fmaf(__expf(dv[i * 4 + 1] * Acoef[n]), hn, du[i * 4 + 1] * Bv.y);
            s[i * 4 + 1] = fmaf(hn, Cv.y, s[i * 4 + 1]);
            hn = fmaf(__expf(dv[i * 4 + 2] * Acoef[n]), hn, du[i * 4 + 2] * Bv.z);
            s[i * 4 + 2] = fmaf(hn, Cv.z, s[i * 4 + 2]);
            hn = fmaf(__expf(dv[i * 4 + 3] * Acoef[n]), hn, du[i * 4 + 3] * Bv.w);
            s[i * 4 + 3] = fmaf(hn, Cv.w, s[i * 4 + 3]);
        }
    }

    // gate + store (lane-contiguous 64B lines)
    {
        const float4* zp = (const float4*)(xzT + row_z);
        float4* yp = (float4*)(yT + row_t);
        #pragma unroll
        for (int i = 0; i < 4; i++) {
            float4 zv = zp[i];
            float4 yv;
            float v0 = s[i * 4 + 0] + uv[i * 4 + 0] * Dd;
            float v1 = s[i * 4 + 1] + uv[i * 4 + 1] * Dd;
            float v2 = s[i * 4 + 2] + uv[i * 4 + 2] * Dd;
            float v3 = s[i * 4 + 3] + uv[i * 4 + 3] * Dd;
            yv.x = v0 * (zv.x / (1.f + __expf(-zv.x)));
            yv.y = v1 * (zv.y / (1.f + __expf(-zv.y)));
            yv.z = v2 * (zv.z / (1.f + __expf(-zv.z)));
            yv.w = v3 * (zv.w / (1.f + __expf(-zv.w)));
            yp[i] = yv;
        }
    }
}

// yT fp32 [DI][BL] -> yB bf16 [BL][DI], 64x64 LDS tiles.
__global__ __launch_bounds__(256) void transpose_cast(const float* __restrict__ yT,
        ushort* __restrict__ yB)
{
    __shared__ float t[64][65];
    const int bl0 = blockIdx.x * 64, d0 = blockIdx.y * 64;
    const int tid = threadIdx.x;
    #pragma unroll
    for (int i = 0; i < 4; i++) {
        int chunk = tid + i * 256;
        int dr = chunk >> 4, c4 = (chunk & 15) * 4;
        const float4 v = *(const float4*)&yT[(size_t)(d0 + dr) * BL + bl0 + c4];
        t[dr][c4 + 0] = v.x; t[dr][c4 + 1] = v.y;
        t[dr][c4 + 2] = v.z; t[dr][c4 + 3] = v.w;
    }
    __syncthreads();
    #pragma unroll
    for (int i = 0; i < 4; i++) {
        int chunk = tid + i * 256;
        int br = chunk >> 4, dc4 = (chunk & 15) * 4;
        ushort4 o;
        o.x = f2bf(t[dc4 + 0][br]); o.y = f2bf(t[dc4 + 1][br]);
        o.z = f2bf(t[dc4 + 2][br]); o.w = f2bf(t[dc4 + 3][br]);
        *(ushort4*)&yB[(size_t)(bl0 + br) * DI + d0 + dc4] = o;
    }
}

// LayerNorm over last dim (512), one block per row, fp32 out.
__global__ __launch_bounds__(256) void ln_kernel(const float* __restrict__ r,
        const float* __restrict__ lnw, const float* __restrict__ lnb,
        float* __restrict__ out)
{
    int row = blockIdx.x;
    const float* rr = r + (size_t)row * DM;
    float v0 = rr[threadIdx.x], v1 = rr[threadIdx.x + 256];
    float s = v0 + v1, s2 = v0 * v0 + v1 * v1;
    #pragma unroll
    for (int off = 32; off > 0; off >>= 1) {
        s  += __shfl_down(s, off);
        s2 += __shfl_down(s2, off);
    }
    __shared__ float ls[4], ls2[4];
    __shared__ float mu_s, rstd_s;
    int wid = threadIdx.x >> 6, lane = threadIdx.x & 63;
    if (lane == 0) { ls[wid] = s; ls2[wid] = s2; }
    __syncthreads();
    if (threadIdx.x == 0) {
        float S = ls[0] + ls[1] + ls[2] + ls[3];
        float S2 = ls2[0] + ls2[1] + ls2[2] + ls2[3];
        float mu = S * (1.f / DM);
        float var = S2 * (1.f / DM) - mu * mu;
        mu_s = mu;
        rstd_s = rsqrtf(var + 1e-5f);
    }
    __syncthreads();
    float mu = mu_s, rstd = rstd_s;
    out[(size_t)row * DM + threadIdx.x] =
        (v0 - mu) * rstd * lnw[threadIdx.x] + lnb[threadIdx.x];
    out[(size_t)row * DM + threadIdx.x + 256] =
        (v1 - mu) * rstd * lnw[threadIdx.x + 256] + lnb[threadIdx.x + 256];
}

extern "C" void kernel_launch(void* const* d_in, const int* in_sizes, int n_in,
                              void* d_out, int out_size, void* d_ws, size_t ws_size,
                              hipStream_t stream)
{
    const float* x         = (const float*)d_in[0];
    const float* in_proj_w = (const float*)d_in[1];
    const float* conv_w    = (const float*)d_in[2];
    const float* conv_b    = (const float*)d_in[3];
    const float* x_proj_w  = (const float*)d_in[4];
    const float* dt_proj_w = (const float*)d_in[5];
    const float* dt_proj_b = (const float*)d_in[6];
    const float* A_log     = (const float*)d_in[7];
    const float* Dvec      = (const float*)d_in[8];
    const float* out_proj_w= (const float*)d_in[9];
    const float* ln_w      = (const float*)d_in[10];
    const float* ln_b      = (const float*)d_in[11];
    float* out = (float*)d_out;

    // fp32 regions (floats)
    float* ws     = (float*)d_ws;
    float* xzT    = ws;                                  // 2048 x 4096 (32 MB)
    float* uT     = xzT    + (size_t)2048 * BL;          // 1024 x 4096 (16 MB)
    float* xdblT  = uT     + (size_t)DI * BL;            // 64 x 4096   (1 MB)
    float* deltaT = xdblT  + (size_t)XDC * BL;           // 1024 x 4096 (16 MB)
    float* yT     = deltaT + (size_t)DI * BL;            // 1024 x 4096 (16 MB)
    float* r      = yT     + (size_t)DI * BL;            // 4096 x 512  (8 MB)
    // aliases over time-dead regions:
    float*  xdblp = yT;                                  // KS*64*BL fl = 4 MB, gemm3 partials
    ushort* yB    = (ushort*)deltaT;                     // deltaT dead after scan

    dim3 blk(256);

    // 1) xzT[e][bl] = in_proj_w @ x^T : M=2048, N=4096, K=512 (MFMA, fp32 staged)
    gemm_mfma<0, true, true><<<dim3(BL / 128, 2048 / 128), blk, 0, stream>>>(
        in_proj_w, x, xzT, DM, BL, nullptr);

    // 2) uT = silu(causal_conv(xsT) + cb)
    conv_silu<<<(DI * BL / 4) / 256, blk, 0, stream>>>(xzT, conv_w, conv_b, uT);

    // 3) xdblT = (u @ x_proj_w^T)^T : transposed split-K partials + reduce
    gemm3_splitk<<<dim3(KS, BL / 32), blk, 0, stream>>>(uT, x_proj_w, xdblp);
    gemm3_reduce<<<(64 * BL / 4) / 256, blk, 0, stream>>>(xdblp, xdblT);

    // 4) deltaT[d][bl] = softplus(dtw[d] . xdblT[0:32][bl] + b) : coalesced gemv
    dt_softplus<<<dim3(BL / 256, DI / 4), blk, 0, stream>>>(
        xdblT, dt_proj_w, dt_proj_b, deltaT);

    // 5) fused selective scan + gate (single-chunk, wave-independent)
    scan_fused<<<B_ * DI / 4, blk, 0, stream>>>(
        deltaT, uT, xdblT, xzT, A_log, Dvec, yT);

    // 6a) yT -> yB (bf16, [bl][d])
    transpose_cast<<<dim3(BL / 64, DI / 64), blk, 0, stream>>>(yT, yB);

    // 6b) r[bl][dm] = y @ out_proj_w^T + x : M=4096, N=512, K=1024
    //     (MFMA 128x64 tile -> 256 blocks = full CU coverage, resid epi)
    gemm_mfma_n64<2, false, true><<<dim3(DM / 64, BL / 128), blk, 0, stream>>>(
        yB, out_proj_w, r, DI, DM, x);

    // 7) LayerNorm -> fp32 out
    ln_kernel<<<BL, blk, 0, stream>>>(r, ln_w, ln_b, out);
}

// Round 14
// 252.786 us; speedup vs baseline: 1.1648x; 1.0091x over previous
//
#include <hip/hip_runtime.h>
#include <hip/hip_bf16.h>
#include <math.h>

// MambaBlock: B=4, L=1024, D_MODEL=512, D_INNER=1024, D_STATE=16, D_CONV=4, DT_RANK=32
// fp32 in/out. 12 dispatches:
//  3x cast_bf16 (pre-cast operands once; staging conversion tax removed) ->
//  gemm1 (MFMA 128x128, bf16 staged) -> conv_silu -> gemm3 splitk (b128 LDS) +
//  reduce (TRANSPOSED out, xdblT [64][BL], L2-resident) -> dt_softplus ->
//  scan v8 (single-chunk, lane owns 16 steps, ONE Kogge-Stone, no LDS/barriers)
//  -> transpose_cast -> gemm6 (MFMA 128x64 tile: 256 blocks = 1/CU) -> LN.
#define B_   4
#define L_   1024
#define DM   512
#define DI   1024
#define NS   16
#define XDC  64      // DT_RANK + 2*D_STATE
#define BL   4096    // B_*L_
#define KS   4       // gemm3 split-K factor

typedef short bfrag __attribute__((ext_vector_type(8)));   // 8 bf16
typedef float ffrag __attribute__((ext_vector_type(4)));   // 4 fp32 acc

__device__ __forceinline__ ushort f2bf(float v) {
    __hip_bfloat16 h = __float2bfloat16(v);
    return *(ushort*)&h;
}

// fp32 -> bf16 cast, 4 elems/thread
__global__ __launch_bounds__(256) void cast_bf16(const float* __restrict__ in,
        ushort* __restrict__ out, int n4)
{
    int i = blockIdx.x * 256 + threadIdx.x;
    if (i >= n4) return;
    float4 v = ((const float4*)in)[i];
    ushort4 o;
    o.x = f2bf(v.x); o.y = f2bf(v.y); o.z = f2bf(v.z); o.w = f2bf(v.w);
    ((ushort4*)out)[i] = o;
}

// stage 8 elements (16B of bf16) into LDS; F32 => convert fp32 source in-register.
template<bool F32>
__device__ __forceinline__ void stage8(const void* p, size_t eoff, ushort* dst) {
    if constexpr (F32) {
        const float* f = (const float*)p + eoff;
        float4 v0 = *(const float4*)f;
        float4 v1 = *(const float4*)(f + 4);
        *(ushort4*)dst       = make_ushort4(f2bf(v0.x), f2bf(v0.y), f2bf(v0.z), f2bf(v0.w));
        *(ushort4*)(dst + 4) = make_ushort4(f2bf(v1.x), f2bf(v1.y), f2bf(v1.z), f2bf(v1.w));
    } else {
        *(uint4*)dst = *(const uint4*)((const ushort*)p + eoff);
    }
}

// MFMA bf16 TN GEMM: C[M,N] = A[M,K] * B[N,K]^T, fp32 out.
// 128x128 block tile, BK=32, 4 waves (2x2), wave tile 64x64 (4x4 of 16x16x32).
// AF/BF: operand source is fp32 (convert during staging) vs pre-cast bf16.
// EPI: 0 none; 2 C += resid[m*ldc+n]
template<int EPI, bool AF, bool BF>
__global__ __launch_bounds__(256) void gemm_mfma(const void* __restrict__ Ap,
        const void* __restrict__ Bp, float* __restrict__ C,
        int K, int ldc, const float* __restrict__ resid)
{
    __shared__ ushort As[128][40];
    __shared__ ushort Bs[128][40];
    const int tid = threadIdx.x;
    const int lane = tid & 63, wave = tid >> 6;
    const int wm = (wave & 1) * 64, wn = (wave >> 1) * 64;
    const int l15 = lane & 15, quad = lane >> 4;
    const int m0 = blockIdx.y * 128, n0 = blockIdx.x * 128;

    ffrag acc[4][4] = {};

    for (int k0 = 0; k0 < K; k0 += 32) {
        #pragma unroll
        for (int i = 0; i < 2; i++) {
            int chunk = tid + i * 256;
            int row = chunk >> 2, kk8 = (chunk & 3) * 8;
            stage8<AF>(Ap, (size_t)(m0 + row) * K + k0 + kk8, &As[row][kk8]);
            stage8<BF>(Bp, (size_t)(n0 + row) * K + k0 + kk8, &Bs[row][kk8]);
        }
        __syncthreads();
        bfrag af[4], bfv[4];
        #pragma unroll
        for (int i = 0; i < 4; i++) {
            af[i]  = *(const bfrag*)&As[wm + i * 16 + l15][quad * 8];
            bfv[i] = *(const bfrag*)&Bs[wn + i * 16 + l15][quad * 8];
        }
        #pragma unroll
        for (int i = 0; i < 4; i++)
            #pragma unroll
            for (int j = 0; j < 4; j++)
                acc[i][j] = __builtin_amdgcn_mfma_f32_16x16x32_bf16(af[i], bfv[j], acc[i][j], 0, 0, 0);
        __syncthreads();
    }

    #pragma unroll
    for (int i = 0; i < 4; i++) {
        #pragma unroll
        for (int j = 0; j < 4; j++) {
            int n = n0 + wn + j * 16 + l15;
            #pragma unroll
            for (int r = 0; r < 4; r++) {
                int m = m0 + wm + i * 16 + quad * 4 + r;
                float v = acc[i][j][r];
                if (EPI == 2) v += resid[(size_t)m * ldc + n];
                C[(size_t)m * ldc + n] = v;
            }
        }
    }
}

// MFMA bf16 TN GEMM, 128x64 tile (for N=512 outputs: grid 8x32 = 256 blocks =
// 1 per CU; the 128x128 tile left half the machine idle at N=512).
// 4 waves 2x2, wave tile 64x32 (4x2 of 16x16x32). EPI=2: C += resid.
template<int EPI, bool AF, bool BF>
__global__ __launch_bounds__(256) void gemm_mfma_n64(const void* __restrict__ Ap,
        const void* __restrict__ Bp, float* __restrict__ C,
        int K, int ldc, const float* __restrict__ resid)
{
    __shared__ ushort As[128][40];
    __shared__ ushort Bs[64][40];
    const int tid = threadIdx.x;
    const int lane = tid & 63, wave = tid >> 6;
    const int wm = (wave & 1) * 64, wn = (wave >> 1) * 32;
    const int l15 = lane & 15, quad = lane >> 4;
    const int m0 = blockIdx.y * 128, n0 = blockIdx.x * 64;

    ffrag acc[4][2] = {};

    for (int k0 = 0; k0 < K; k0 += 32) {
        #pragma unroll
        for (int i = 0; i < 2; i++) {
            int chunk = tid + i * 256;
            int row = chunk >> 2, kk8 = (chunk & 3) * 8;
            stage8<AF>(Ap, (size_t)(m0 + row) * K + k0 + kk8, &As[row][kk8]);
        }
        {
            int row = tid >> 2, kk8 = (tid & 3) * 8;
            stage8<BF>(Bp, (size_t)(n0 + row) * K + k0 + kk8, &Bs[row][kk8]);
        }
        __syncthreads();
        bfrag af[4], bfv[2];
        #pragma unroll
        for (int i = 0; i < 4; i++)
            af[i] = *(const bfrag*)&As[wm + i * 16 + l15][quad * 8];
        #pragma unroll
        for (int j = 0; j < 2; j++)
            bfv[j] = *(const bfrag*)&Bs[wn + j * 16 + l15][quad * 8];
        #pragma unroll
        for (int i = 0; i < 4; i++)
            #pragma unroll
            for (int j = 0; j < 2; j++)
                acc[i][j] = __builtin_amdgcn_mfma_f32_16x16x32_bf16(af[i], bfv[j], acc[i][j], 0, 0, 0);
        __syncthreads();
    }

    #pragma unroll
    for (int i = 0; i < 4; i++) {
        #pragma unroll
        for (int j = 0; j < 2; j++) {
            int n = n0 + wn + j * 16 + l15;
            #pragma unroll
            for (int r = 0; r < 4; r++) {
                int m = m0 + wm + i * 16 + quad * 4 + r;
                float v = acc[i][j][r];
                if (EPI == 2) v += resid[(size_t)m * ldc + n];
                C[(size_t)m * ldc + n] = v;
            }
        }
    }
}

// gemm3 split-K, TRANSPOSED output: part[ks][n][m] = sum over K-chunk of u[m][k]*W[n][k].
// A = uT [K=DI][M=BL], W = x_proj_w [64][DI].
// Block: 32 m-rows x 64 n-cols, K-chunk = DI/KS = 256, BK=16.
// As stride 36 floats (144B, 16B-aligned rows) so the wave-uniform A reads are
// 2x ds_read_b128 (was 8x scalar b32): inner loop 3 LDS reads + 8 fma.
__global__ __launch_bounds__(256) void gemm3_splitk(const float* __restrict__ uT,
        const float* __restrict__ xw, float* __restrict__ part)
{
    __shared__ float As[16][36];    // [k][m] 32 m, 16B-aligned rows
    __shared__ float Ws[16][68];    // [k][n] 64 n
    const int tid = threadIdx.x;
    const int nn = tid & 63;
    const int mg = tid >> 6;        // 0..3
    const int ks = blockIdx.x, m0 = blockIdx.y * 32;
    const int kbase = ks * (DI / KS);
    float acc[8] = {};

    for (int k0 = 0; k0 < DI / KS; k0 += 16) {
        if (tid < 128) {
            int k = tid >> 3, m4 = (tid & 7) * 4;
            const float4 v = *(const float4*)&uT[(size_t)(kbase + k0 + k) * BL + m0 + m4];
            *(float4*)&As[k][m4] = v;
        }
        {
            int r = tid >> 2, c4 = (tid & 3) * 4;
            const float4 v = *(const float4*)&xw[(size_t)r * DI + kbase + k0 + c4];
            Ws[c4 + 0][r] = v.x; Ws[c4 + 1][r] = v.y;
            Ws[c4 + 2][r] = v.z; Ws[c4 + 3][r] = v.w;
        }
        __syncthreads();
        #pragma unroll
        for (int kk = 0; kk < 16; kk++) {
            float w = Ws[kk][nn];
            float4 a0 = *(const float4*)&As[kk][mg * 8];
            float4 a1 = *(const float4*)&As[kk][mg * 8 + 4];
            acc[0] = fmaf(a0.x, w, acc[0]);
            acc[1] = fmaf(a0.y, w, acc[1]);
            acc[2] = fmaf(a0.z, w, acc[2]);
            acc[3] = fmaf(a0.w, w, acc[3]);
            acc[4] = fmaf(a1.x, w, acc[4]);
            acc[5] = fmaf(a1.y, w, acc[5]);
            acc[6] = fmaf(a1.z, w, acc[6]);
            acc[7] = fmaf(a1.w, w, acc[7]);
        }
        __syncthreads();
    }

    float* pp = part + (size_t)ks * 64 * BL + (size_t)nn * BL + m0 + mg * 8;
    *(float4*)&pp[0] = make_float4(acc[0], acc[1], acc[2], acc[3]);
    *(float4*)&pp[4] = make_float4(acc[4], acc[5], acc[6], acc[7]);
}

// reduce KS transposed partials -> xdblT [64][BL] fp32.
__global__ __launch_bounds__(256) void gemm3_reduce(const float* __restrict__ part,
        float* __restrict__ xdblT)
{
    int i = blockIdx.x * 256 + threadIdx.x;     // over 64*BL/4
    const float4* p0 = (const float4*)part;
    float4 a = p0[i];
    #pragma unroll
    for (int s = 1; s < KS; s++) {
        float4 b = p0[i + (size_t)s * 64 * BL / 4];
        a.x += b.x; a.y += b.y; a.z += b.z; a.w += b.w;
    }
    ((float4*)xdblT)[i] = a;
}

// delta[d][bl] = softplus(sum_k dtw[d][k] * xdblT[k][bl] + bias[d])
// Block: 4 waves; wave w owns d = blockIdx.y*4 + w. Thread owns one float4 of bl.
// All loads coalesced (row k of xdblT, 1KB per wave per k); xdblT is L2-resident.
__global__ __launch_bounds__(256) void dt_softplus(const float* __restrict__ xdblT,
        const float* __restrict__ dtw, const float* __restrict__ bias,
        float* __restrict__ deltaT)
{
    const int tid = threadIdx.x;
    const int lane = tid & 63;
    const int bl = blockIdx.x * 256 + lane * 4;

    int d = blockIdx.y * 4 + (tid >> 6);
    d = __builtin_amdgcn_readfirstlane(d);
    float wreg[32];
    {
        const float4* wp = (const float4*)(dtw + (size_t)d * 32);
        #pragma unroll
        for (int k = 0; k < 8; k++) *(float4*)&wreg[k * 4] = wp[k];
    }
    const float bb = bias[d];

    float4 acc = make_float4(bb, bb, bb, bb);
    #pragma unroll
    for (int k = 0; k < 32; k++) {
        float4 v = *(const float4*)&xdblT[(size_t)k * BL + bl];
        float w = wreg[k];
        acc.x = fmaf(w, v.x, acc.x);
        acc.y = fmaf(w, v.y, acc.y);
        acc.z = fmaf(w, v.z, acc.z);
        acc.w = fmaf(w, v.w, acc.w);
    }
    float4 o;
    o.x = (acc.x > 20.f) ? acc.x : __logf(1.f + __expf(acc.x));
    o.y = (acc.y > 20.f) ? acc.y : __logf(1.f + __expf(acc.y));
    o.z = (acc.z > 20.f) ? acc.z : __logf(1.f + __expf(acc.z));
    o.w = (acc.w > 20.f) ? acc.w : __logf(1.f + __expf(acc.w));
    *(float4*)&deltaT[(size_t)d * BL + bl] = o;
}

// depthwise causal conv (k=4) + bias + SiLU, channel-major, 4 outputs/thread.
__global__ __launch_bounds__(256) void conv_silu(const float* __restrict__ xzT,
        const float* __restrict__ cw, const float* __restrict__ cb,
        float* __restrict__ uT)
{
    int i = blockIdx.x * 256 + threadIdx.x;     // over DI*BL/4
    int d  = i >> 10;
    int q  = i & 1023;
    int bl = q * 4;
    int l  = bl & (L_ - 1);
    const float* row = xzT + (size_t)d * BL;
    float4 cur = *(const float4*)&row[bl];
    float4 prev = make_float4(0.f, 0.f, 0.f, 0.f);
    if (l != 0) prev = *(const float4*)&row[bl - 4];
    float v[7] = { prev.y, prev.z, prev.w, cur.x, cur.y, cur.z, cur.w };
    float w0 = cw[d * 4 + 0], w1 = cw[d * 4 + 1], w2 = cw[d * 4 + 2], w3 = cw[d * 4 + 3];
    float bias = cb[d];
    float4 o;
    o.x = bias + w0 * v[0] + w1 * v[1] + w2 * v[2] + w3 * v[3];
    o.y = bias + w0 * v[1] + w1 * v[2] + w2 * v[3] + w3 * v[4];
    o.z = bias + w0 * v[2] + w1 * v[3] + w2 * v[4] + w3 * v[5];
    o.w = bias + w0 * v[3] + w1 * v[4] + w2 * v[5] + w3 * v[6];
    o.x = o.x / (1.f + __expf(-o.x));
    o.y = o.y / (1.f + __expf(-o.y));
    o.z = o.z / (1.f + __expf(-o.z));
    o.w = o.w / (1.f + __expf(-o.w));
    *(float4*)&uT[(size_t)d * BL + bl] = o;
}

// ---- selective scan v8: single-chunk, barrier-free, LDS-free ----
// Block = 4 waves = 4 (b,d); wave owns one (b,d). Lane k owns timesteps
// [16k, 16k+16) (64 lanes x 16 = L); all 16 n-states live in registers.
//  - B/C read DIRECTLY from xdblT rows (32+n / 48+n): lane reads its own 64B
//    line; wave covers 4KB contiguous -> line-coalesced, L2-resident (1 MB)
//  - phase 1: 16-step local affine summary (a = exp(Acoef*sum_dv), bb = h_end|0)
//  - ONE Kogge-Stone shfl scan over 64 lanes (6 rounds); h0 = exclusive prefix
//  - phase 2: 16-step rescan + local C-contraction; gate; store
//  - no inter-chunk carry, no __syncthreads, no LDS.
__global__ __launch_bounds__(256) void scan_fused(const float* __restrict__ deltaT,
        const float* __restrict__ uT, const float* __restrict__ xdblT,
        const float* __restrict__ xzT, const float* __restrict__ A_log,
        const float* __restrict__ Dp, float* __restrict__ yT)
{
    const int tid = threadIdx.x;
    const int lane = tid & 63;
    const int bd = blockIdx.x * 4 + (tid >> 6);
    const int d = bd & (DI - 1);
    const int b = bd >> 10;

    float Acoef[16];
    {
        const float4* ap = (const float4*)(A_log + d * NS);
        #pragma unroll
        for (int i = 0; i < 4; i++) {
            float4 v = ap[i];
            Acoef[i * 4 + 0] = -__expf(v.x); Acoef[i * 4 + 1] = -__expf(v.y);
            Acoef[i * 4 + 2] = -__expf(v.z); Acoef[i * 4 + 3] = -__expf(v.w);
        }
    }
    const float Dd = Dp[d];

    const size_t row_t = (size_t)d * BL + b * L_ + lane * 16;
    const size_t row_z = (size_t)(DI + d) * BL + b * L_ + lane * 16;
    const float* xB = xdblT + (size_t)32 * BL + b * L_ + lane * 16;  // B row n: +n*BL
    const float* xC = xdblT + (size_t)48 * BL + b * L_ + lane * 16;  // C row n: +n*BL

    // load 16 steps of delta, u (lane-contiguous 64B lines)
    float dv[16], uv[16];
    {
        const float4* dp = (const float4*)(deltaT + row_t);
        const float4* up = (const float4*)(uT + row_t);
        #pragma unroll
        for (int i = 0; i < 4; i++) {
            *(float4*)&dv[i * 4] = dp[i];
            *(float4*)&uv[i * 4] = up[i];
        }
    }
    float du[16];
    float sa = 0.f;
    #pragma unroll
    for (int j = 0; j < 16; j++) { du[j] = dv[j] * uv[j]; sa += dv[j]; }

    // ---- phase 1: local summary (a, bb) per n ----
    float a[16], bb[16];
    #pragma unroll
    for (int n = 0; n < 16; n++) {
        a[n] = __expf(sa * Acoef[n]);
        const float4* bp = (const float4*)(xB + (size_t)n * BL);
        float acc;
        #pragma unroll
        for (int i = 0; i < 4; i++) {
            float4 Bv = bp[i];
            if (i == 0) acc = du[0] * Bv.x;
            else        acc = fmaf(__expf(dv[i * 4] * Acoef[n]), acc, du[i * 4] * Bv.x);
            acc = fmaf(__expf(dv[i * 4 + 1] * Acoef[n]), acc, du[i * 4 + 1] * Bv.y);
            acc = fmaf(__expf(dv[i * 4 + 2] * Acoef[n]), acc, du[i * 4 + 2] * Bv.z);
            acc = fmaf(__expf(dv[i * 4 + 3] * Acoef[n]), acc, du[i * 4 + 3] * Bv.w);
        }
        bb[n] = acc;
    }

    // ---- ONE Kogge-Stone inclusive scan of affine maps over 64 lanes ----
    #pragma unroll
    for (int off = 1; off < 64; off <<= 1) {
        #pragma unroll
        for (int n = 0; n < 16; n++) {
            float pa = __shfl_up(a[n], off);
            float pb = __shfl_up(bb[n], off);
            if (lane >= off) {
                bb[n] = fmaf(a[n], pb, bb[n]);   // uses OLD a (newer ∘ older)
                a[n] *= pa;
            }
        }
    }

    // exclusive prefix -> h0 for this lane's 16 steps (global h0 = 0)
    float h[16];
    #pragma unroll
    for (int n = 0; n < 16; n++) {
        float pb = __shfl_up(bb[n], 1);
        h[n] = (lane == 0) ? 0.f : pb;
    }

    // ---- phase 2: rescan 16 steps + C-contraction ----
    float s[16];
    #pragma unroll
    for (int j = 0; j < 16; j++) s[j] = 0.f;
    #pragma unroll
    for (int n = 0; n < 16; n++) {
        const float4* bp = (const float4*)(xB + (size_t)n * BL);
        const float4* cp = (const float4*)(xC + (size_t)n * BL);
        float hn = h[n];
        #pragma unroll
        for (int i = 0; i < 4; i++) {
            float4 Bv = bp[i];
            float4 Cv = cp[i];
            hn = fmaf(__expf(dv[i * 4 + 0] * Acoef[n]), hn, du[i * 4 + 0] * Bv.x);
            s[i * 4 + 0] = fmaf(hn, Cv.x, s[i * 4 + 0]);
            hn = fmaf(__expf(dv[i * 4 + 1] * Acoef[n]), hn, du[i * 4 + 1] * Bv.y);
            s[i * 4 + 1] = fmaf(hn, Cv.y, s[i * 4 + 1]);
            hn = fmaf(__expf(dv[i * 4 + 2] * Acoef[n]), hn, du[i * 4 + 2] * Bv.z);
            s[i * 4 + 2] = fmaf(hn, Cv.z, s[i * 4 + 2]);
            hn = fmaf(__expf(dv[i * 4 + 3] * Acoef[n]), hn, du[i * 4 + 3] * Bv.w);
            s[i * 4 + 3] = fmaf(hn, Cv.w, s[i * 4 + 3]);
        }
    }

    // gate + store (lane-contiguous 64B lines)
    {
        const float4* zp = (const float4*)(xzT + row_z);
        float4* yp = (float4*)(yT + row_t);
        #pragma unroll
        for (int i = 0; i < 4; i++) {
            float4 zv = zp[i];
            float4 yv;
            float v0 = s[i * 4 + 0] + uv[i * 4 + 0] * Dd;
            float v1 = s[i * 4 + 1] + uv[i * 4 + 1] * Dd;
            float v2 = s[i * 4 + 2] + uv[i * 4 + 2] * Dd;
            float v3 = s[i * 4 + 3] + uv[i * 4 + 3] * Dd;
            yv.x = v0 * (zv.x / (1.f + __expf(-zv.x)));
            yv.y = v1 * (zv.y / (1.f + __expf(-zv.y)));
            yv.z = v2 * (zv.z / (1.f + __expf(-zv.z)));
            yv.w = v3 * (zv.w / (1.f + __expf(-zv.w)));
            yp[i] = yv;
        }
    }
}

// yT fp32 [DI][BL] -> yB bf16 [BL][DI], 64x64 LDS tiles.
__global__ __launch_bounds__(256) void transpose_cast(const float* __restrict__ yT,
        ushort* __restrict__ yB)
{
    __shared__ float t[64][65];
    const int bl0 = blockIdx.x * 64, d0 = blockIdx.y * 64;
    const int tid = threadIdx.x;
    #pragma unroll
    for (int i = 0; i < 4; i++) {
        int chunk = tid + i * 256;
        int dr = chunk >> 4, c4 = (chunk & 15) * 4;
        const float4 v = *(const float4*)&yT[(size_t)(d0 + dr) * BL + bl0 + c4];
        t[dr][c4 + 0] = v.x; t[dr][c4 + 1] = v.y;
        t[dr][c4 + 2] = v.z; t[dr][c4 + 3] = v.w;
    }
    __syncthreads();
    #pragma unroll
    for (int i = 0; i < 4; i++) {
        int chunk = tid + i * 256;
        int br = chunk >> 4, dc4 = (chunk & 15) * 4;
        ushort4 o;
        o.x = f2bf(t[dc4 + 0][br]); o.y = f2bf(t[dc4 + 1][br]);
        o.z = f2bf(t[dc4 + 2][br]); o.w = f2bf(t[dc4 + 3][br]);
        *(ushort4*)&yB[(size_t)(bl0 + br) * DI + d0 + dc4] = o;
    }
}

// LayerNorm over last dim (512), one block per row, fp32 out.
__global__ __launch_bounds__(256) void ln_kernel(const float* __restrict__ r,
        const float* __restrict__ lnw, const float* __restrict__ lnb,
        float* __restrict__ out)
{
    int row = blockIdx.x;
    const float* rr = r + (size_t)row * DM;
    float v0 = rr[threadIdx.x], v1 = rr[threadIdx.x + 256];
    float s = v0 + v1, s2 = v0 * v0 + v1 * v1;
    #pragma unroll
    for (int off = 32; off > 0; off >>= 1) {
        s  += __shfl_down(s, off);
        s2 += __shfl_down(s2, off);
    }
    __shared__ float ls[4], ls2[4];
    __shared__ float mu_s, rstd_s;
    int wid = threadIdx.x >> 6, lane = threadIdx.x & 63;
    if (lane == 0) { ls[wid] = s; ls2[wid] = s2; }
    __syncthreads();
    if (threadIdx.x == 0) {
        float S = ls[0] + ls[1] + ls[2] + ls[3];
        float S2 = ls2[0] + ls2[1] + ls2[2] + ls2[3];
        float mu = S * (1.f / DM);
        float var = S2 * (1.f / DM) - mu * mu;
        mu_s = mu;
        rstd_s = rsqrtf(var + 1e-5f);
    }
    __syncthreads();
    float mu = mu_s, rstd = rstd_s;
    out[(size_t)row * DM + threadIdx.x] =
        (v0 - mu) * rstd * lnw[threadIdx.x] + lnb[threadIdx.x];
    out[(size_t)row * DM + threadIdx.x + 256] =
        (v1 - mu) * rstd * lnw[threadIdx.x + 256] + lnb[threadIdx.x + 256];
}

extern "C" void kernel_launch(void* const* d_in, const int* in_sizes, int n_in,
                              void* d_out, int out_size, void* d_ws, size_t ws_size,
                              hipStream_t stream)
{
    const float* x         = (const float*)d_in[0];
    const float* in_proj_w = (const float*)d_in[1];
    const float* conv_w    = (const float*)d_in[2];
    const float* conv_b    = (const float*)d_in[3];
    const float* x_proj_w  = (const float*)d_in[4];
    const float* dt_proj_w = (const float*)d_in[5];
    const float* dt_proj_b = (const float*)d_in[6];
    const float* A_log     = (const float*)d_in[7];
    const float* Dvec      = (const float*)d_in[8];
    const float* out_proj_w= (const float*)d_in[9];
    const float* ln_w      = (const float*)d_in[10];
    const float* ln_b      = (const float*)d_in[11];
    float* out = (float*)d_out;

    // fp32 regions (floats)
    float* ws     = (float*)d_ws;
    float* xzT    = ws;                                  // 2048 x 4096 (32 MB)
    float* uT     = xzT    + (size_t)2048 * BL;          // 1024 x 4096 (16 MB)
    float* xdblT  = uT     + (size_t)DI * BL;            // 64 x 4096   (1 MB)
    float* deltaT = xdblT  + (size_t)XDC * BL;           // 1024 x 4096 (16 MB)
    float* yT     = deltaT + (size_t)DI * BL;            // 1024 x 4096 (16 MB)
    float* r      = yT     + (size_t)DI * BL;            // 4096 x 512  (8 MB)
    // aliases over time-dead regions:
    float*  xdblp = yT;                  // gemm3 partials (4 MB); written after xB dead
    ushort* yB    = (ushort*)deltaT;     // deltaT dead after scan
    ushort* xB    = (ushort*)yT;         // x bf16 (4 MB); dead after gemm1, before xdblp
    ushort* wInB  = (ushort*)deltaT;     // in_proj_w bf16 (2 MB); dead after gemm1
    ushort* wOutB = (ushort*)(r + (size_t)BL * DM);  // out_proj_w bf16 (1 MB); fresh space

    dim3 blk(256);

    // 0) pre-cast operands to bf16 (once; removes per-iter staging conversions)
    cast_bf16<<<(BL * DM / 4 + 255) / 256, blk, 0, stream>>>(x, xB, BL * DM / 4);
    cast_bf16<<<(2048 * DM / 4 + 255) / 256, blk, 0, stream>>>(in_proj_w, wInB, 2048 * DM / 4);
    cast_bf16<<<(DM * DI / 4 + 255) / 256, blk, 0, stream>>>(out_proj_w, wOutB, DM * DI / 4);

    // 1) xzT[e][bl] = in_proj_w @ x^T : M=2048, N=4096, K=512 (MFMA, bf16 staged)
    gemm_mfma<0, false, false><<<dim3(BL / 128, 2048 / 128), blk, 0, stream>>>(
        wInB, xB, xzT, DM, BL, nullptr);

    // 2) uT = silu(causal_conv(xsT) + cb)
    conv_silu<<<(DI * BL / 4) / 256, blk, 0, stream>>>(xzT, conv_w, conv_b, uT);

    // 3) xdblT = (u @ x_proj_w^T)^T : transposed split-K partials + reduce
    gemm3_splitk<<<dim3(KS, BL / 32), blk, 0, stream>>>(uT, x_proj_w, xdblp);
    gemm3_reduce<<<(64 * BL / 4) / 256, blk, 0, stream>>>(xdblp, xdblT);

    // 4) deltaT[d][bl] = softplus(dtw[d] . xdblT[0:32][bl] + b) : coalesced gemv
    dt_softplus<<<dim3(BL / 256, DI / 4), blk, 0, stream>>>(
        xdblT, dt_proj_w, dt_proj_b, deltaT);

    // 5) fused selective scan + gate (single-chunk, wave-independent)
    scan_fused<<<B_ * DI / 4, blk, 0, stream>>>(
        deltaT, uT, xdblT, xzT, A_log, Dvec, yT);

    // 6a) yT -> yB (bf16, [bl][d])
    transpose_cast<<<dim3(BL / 64, DI / 64), blk, 0, stream>>>(yT, yB);

    // 6b) r[bl][dm] = y @ out_proj_w^T + x : M=4096, N=512, K=1024
    //     (MFMA 128x64 tile -> 256 blocks = full CU coverage, resid epi)
    gemm_mfma_n64<2, false, false><<<dim3(DM / 64, BL / 128), blk, 0, stream>>>(
        yB, wOutB, r, DI, DM, x);

    // 7) LayerNorm -> fp32 out
    ln_kernel<<<BL, blk, 0, stream>>>(r, ln_w, ln_b, out);
}

// Round 15
// 247.027 us; speedup vs baseline: 1.1919x; 1.0233x over previous
//
#include <hip/hip_runtime.h>
#include <hip/hip_bf16.h>
#include <math.h>

// MambaBlock: B=4, L=1024, D_MODEL=512, D_INNER=1024, D_STATE=16, D_CONV=4, DT_RANK=32
// fp32 in/out. 10 dispatches:
//  cast3 (all bf16 operand pre-casts in ONE launch) ->
//  gemm1 (MFMA 128x128, bf16 staged) -> conv_silu -> gemm3 splitk (b128 LDS) +
//  reduce (TRANSPOSED out, xdblT [64][BL], L2-resident) -> dt_softplus ->
//  scan v8 (single-chunk, lane owns 16 steps, ONE Kogge-Stone, no LDS/barriers)
//  -> transpose_cast -> gemm6 (MFMA 128x64 tile: 256 blocks = 1/CU) -> LN.
#define B_   4
#define L_   1024
#define DM   512
#define DI   1024
#define NS   16
#define XDC  64      // DT_RANK + 2*D_STATE
#define BL   4096    // B_*L_
#define KS   4       // gemm3 split-K factor

typedef short bfrag __attribute__((ext_vector_type(8)));   // 8 bf16
typedef float ffrag __attribute__((ext_vector_type(4)));   // 4 fp32 acc

__device__ __forceinline__ ushort f2bf(float v) {
    __hip_bfloat16 h = __float2bfloat16(v);
    return *(ushort*)&h;
}

#define N4_X   (BL * DM / 4)        // 524288
#define N4_WIN (2048 * DM / 4)      // 262144
#define N4_WOUT (DM * DI / 4)       // 131072

// one-launch fp32->bf16 pre-cast of x, in_proj_w, out_proj_w (4 elems/thread)
__global__ __launch_bounds__(256) void cast3(const float* __restrict__ x,
        ushort* __restrict__ xB, const float* __restrict__ win,
        ushort* __restrict__ wInB, const float* __restrict__ wout,
        ushort* __restrict__ wOutB)
{
    int i = blockIdx.x * 256 + threadIdx.x;
    const float* src; ushort* dst; int j;
    if (i < N4_X)                   { src = x;    dst = xB;    j = i; }
    else if (i < N4_X + N4_WIN)     { src = win;  dst = wInB;  j = i - N4_X; }
    else if (i < N4_X + N4_WIN + N4_WOUT) { src = wout; dst = wOutB; j = i - N4_X - N4_WIN; }
    else return;
    float4 v = ((const float4*)src)[j];
    ushort4 o;
    o.x = f2bf(v.x); o.y = f2bf(v.y); o.z = f2bf(v.z); o.w = f2bf(v.w);
    ((ushort4*)dst)[j] = o;
}

// stage 8 elements (16B of bf16) into LDS; F32 => convert fp32 source in-register.
template<bool F32>
__device__ __forceinline__ void stage8(const void* p, size_t eoff, ushort* dst) {
    if constexpr (F32) {
        const float* f = (const float*)p + eoff;
        float4 v0 = *(const float4*)f;
        float4 v1 = *(const float4*)(f + 4);
        *(ushort4*)dst       = make_ushort4(f2bf(v0.x), f2bf(v0.y), f2bf(v0.z), f2bf(v0.w));
        *(ushort4*)(dst + 4) = make_ushort4(f2bf(v1.x), f2bf(v1.y), f2bf(v1.z), f2bf(v1.w));
    } else {
        *(uint4*)dst = *(const uint4*)((const ushort*)p + eoff);
    }
}

// MFMA bf16 TN GEMM: C[M,N] = A[M,K] * B[N,K]^T, fp32 out.
// 128x128 block tile, BK=32, 4 waves (2x2), wave tile 64x64 (4x4 of 16x16x32).
// EPI: 0 none; 2 C += resid[m*ldc+n]
template<int EPI, bool AF, bool BF>
__global__ __launch_bounds__(256) void gemm_mfma(const void* __restrict__ Ap,
        const void* __restrict__ Bp, float* __restrict__ C,
        int K, int ldc, const float* __restrict__ resid)
{
    __shared__ ushort As[128][40];
    __shared__ ushort Bs[128][40];
    const int tid = threadIdx.x;
    const int lane = tid & 63, wave = tid >> 6;
    const int wm = (wave & 1) * 64, wn = (wave >> 1) * 64;
    const int l15 = lane & 15, quad = lane >> 4;
    const int m0 = blockIdx.y * 128, n0 = blockIdx.x * 128;

    ffrag acc[4][4] = {};

    for (int k0 = 0; k0 < K; k0 += 32) {
        #pragma unroll
        for (int i = 0; i < 2; i++) {
            int chunk = tid + i * 256;
            int row = chunk >> 2, kk8 = (chunk & 3) * 8;
            stage8<AF>(Ap, (size_t)(m0 + row) * K + k0 + kk8, &As[row][kk8]);
            stage8<BF>(Bp, (size_t)(n0 + row) * K + k0 + kk8, &Bs[row][kk8]);
        }
        __syncthreads();
        bfrag af[4], bfv[4];
        #pragma unroll
        for (int i = 0; i < 4; i++) {
            af[i]  = *(const bfrag*)&As[wm + i * 16 + l15][quad * 8];
            bfv[i] = *(const bfrag*)&Bs[wn + i * 16 + l15][quad * 8];
        }
        #pragma unroll
        for (int i = 0; i < 4; i++)
            #pragma unroll
            for (int j = 0; j < 4; j++)
                acc[i][j] = __builtin_amdgcn_mfma_f32_16x16x32_bf16(af[i], bfv[j], acc[i][j], 0, 0, 0);
        __syncthreads();
    }

    #pragma unroll
    for (int i = 0; i < 4; i++) {
        #pragma unroll
        for (int j = 0; j < 4; j++) {
            int n = n0 + wn + j * 16 + l15;
            #pragma unroll
            for (int r = 0; r < 4; r++) {
                int m = m0 + wm + i * 16 + quad * 4 + r;
                float v = acc[i][j][r];
                if (EPI == 2) v += resid[(size_t)m * ldc + n];
                C[(size_t)m * ldc + n] = v;
            }
        }
    }
}

// MFMA bf16 TN GEMM, 128x64 tile (for N=512 outputs: grid 8x32 = 256 blocks =
// 1 per CU; the 128x128 tile left half the machine idle at N=512).
// 4 waves 2x2, wave tile 64x32 (4x2 of 16x16x32). EPI=2: C += resid.
template<int EPI, bool AF, bool BF>
__global__ __launch_bounds__(256) void gemm_mfma_n64(const void* __restrict__ Ap,
        const void* __restrict__ Bp, float* __restrict__ C,
        int K, int ldc, const float* __restrict__ resid)
{
    __shared__ ushort As[128][40];
    __shared__ ushort Bs[64][40];
    const int tid = threadIdx.x;
    const int lane = tid & 63, wave = tid >> 6;
    const int wm = (wave & 1) * 64, wn = (wave >> 1) * 32;
    const int l15 = lane & 15, quad = lane >> 4;
    const int m0 = blockIdx.y * 128, n0 = blockIdx.x * 64;

    ffrag acc[4][2] = {};

    for (int k0 = 0; k0 < K; k0 += 32) {
        #pragma unroll
        for (int i = 0; i < 2; i++) {
            int chunk = tid + i * 256;
            int row = chunk >> 2, kk8 = (chunk & 3) * 8;
            stage8<AF>(Ap, (size_t)(m0 + row) * K + k0 + kk8, &As[row][kk8]);
        }
        {
            int row = tid >> 2, kk8 = (tid & 3) * 8;
            stage8<BF>(Bp, (size_t)(n0 + row) * K + k0 + kk8, &Bs[row][kk8]);
        }
        __syncthreads();
        bfrag af[4], bfv[2];
        #pragma unroll
        for (int i = 0; i < 4; i++)
            af[i] = *(const bfrag*)&As[wm + i * 16 + l15][quad * 8];
        #pragma unroll
        for (int j = 0; j < 2; j++)
            bfv[j] = *(const bfrag*)&Bs[wn + j * 16 + l15][quad * 8];
        #pragma unroll
        for (int i = 0; i < 4; i++)
            #pragma unroll
            for (int j = 0; j < 2; j++)
                acc[i][j] = __builtin_amdgcn_mfma_f32_16x16x32_bf16(af[i], bfv[j], acc[i][j], 0, 0, 0);
        __syncthreads();
    }

    #pragma unroll
    for (int i = 0; i < 4; i++) {
        #pragma unroll
        for (int j = 0; j < 2; j++) {
            int n = n0 + wn + j * 16 + l15;
            #pragma unroll
            for (int r = 0; r < 4; r++) {
                int m = m0 + wm + i * 16 + quad * 4 + r;
                float v = acc[i][j][r];
                if (EPI == 2) v += resid[(size_t)m * ldc + n];
                C[(size_t)m * ldc + n] = v;
            }
        }
    }
}

// gemm3 split-K, TRANSPOSED output: part[ks][n][m] = sum over K-chunk of u[m][k]*W[n][k].
// A = uT [K=DI][M=BL], W = x_proj_w [64][DI].
// Block: 32 m-rows x 64 n-cols, K-chunk = DI/KS = 256, BK=16.
// As stride 36 floats (144B, 16B-aligned rows) so the wave-uniform A reads are
// 2x ds_read_b128: inner loop 3 LDS reads + 8 fma.
__global__ __launch_bounds__(256) void gemm3_splitk(const float* __restrict__ uT,
        const float* __restrict__ xw, float* __restrict__ part)
{
    __shared__ float As[16][36];    // [k][m] 32 m, 16B-aligned rows
    __shared__ float Ws[16][68];    // [k][n] 64 n
    const int tid = threadIdx.x;
    const int nn = tid & 63;
    const int mg = tid >> 6;        // 0..3
    const int ks = blockIdx.x, m0 = blockIdx.y * 32;
    const int kbase = ks * (DI / KS);
    float acc[8] = {};

    for (int k0 = 0; k0 < DI / KS; k0 += 16) {
        if (tid < 128) {
            int k = tid >> 3, m4 = (tid & 7) * 4;
            const float4 v = *(const float4*)&uT[(size_t)(kbase + k0 + k) * BL + m0 + m4];
            *(float4*)&As[k][m4] = v;
        }
        {
            int r = tid >> 2, c4 = (tid & 3) * 4;
            const float4 v = *(const float4*)&xw[(size_t)r * DI + kbase + k0 + c4];
            Ws[c4 + 0][r] = v.x; Ws[c4 + 1][r] = v.y;
            Ws[c4 + 2][r] = v.z; Ws[c4 + 3][r] = v.w;
        }
        __syncthreads();
        #pragma unroll
        for (int kk = 0; kk < 16; kk++) {
            float w = Ws[kk][nn];
            float4 a0 = *(const float4*)&As[kk][mg * 8];
            float4 a1 = *(const float4*)&As[kk][mg * 8 + 4];
            acc[0] = fmaf(a0.x, w, acc[0]);
            acc[1] = fmaf(a0.y, w, acc[1]);
            acc[2] = fmaf(a0.z, w, acc[2]);
            acc[3] = fmaf(a0.w, w, acc[3]);
            acc[4] = fmaf(a1.x, w, acc[4]);
            acc[5] = fmaf(a1.y, w, acc[5]);
            acc[6] = fmaf(a1.z, w, acc[6]);
            acc[7] = fmaf(a1.w, w, acc[7]);
        }
        __syncthreads();
    }

    float* pp = part + (size_t)ks * 64 * BL + (size_t)nn * BL + m0 + mg * 8;
    *(float4*)&pp[0] = make_float4(acc[0], acc[1], acc[2], acc[3]);
    *(float4*)&pp[4] = make_float4(acc[4], acc[5], acc[6], acc[7]);
}

// reduce KS transposed partials -> xdblT [64][BL] fp32.
__global__ __launch_bounds__(256) void gemm3_reduce(const float* __restrict__ part,
        float* __restrict__ xdblT)
{
    int i = blockIdx.x * 256 + threadIdx.x;     // over 64*BL/4
    const float4* p0 = (const float4*)part;
    float4 a = p0[i];
    #pragma unroll
    for (int s = 1; s < KS; s++) {
        float4 b = p0[i + (size_t)s * 64 * BL / 4];
        a.x += b.x; a.y += b.y; a.z += b.z; a.w += b.w;
    }
    ((float4*)xdblT)[i] = a;
}

// delta[d][bl] = softplus(sum_k dtw[d][k] * xdblT[k][bl] + bias[d])
// Block: 4 waves; wave w owns d = blockIdx.y*4 + w. Thread owns one float4 of bl.
__global__ __launch_bounds__(256) void dt_softplus(const float* __restrict__ xdblT,
        const float* __restrict__ dtw, const float* __restrict__ bias,
        float* __restrict__ deltaT)
{
    const int tid = threadIdx.x;
    const int lane = tid & 63;
    const int bl = blockIdx.x * 256 + lane * 4;

    int d = blockIdx.y * 4 + (tid >> 6);
    d = __builtin_amdgcn_readfirstlane(d);
    float wreg[32];
    {
        const float4* wp = (const float4*)(dtw + (size_t)d * 32);
        #pragma unroll
        for (int k = 0; k < 8; k++) *(float4*)&wreg[k * 4] = wp[k];
    }
    const float bb = bias[d];

    float4 acc = make_float4(bb, bb, bb, bb);
    #pragma unroll
    for (int k = 0; k < 32; k++) {
        float4 v = *(const float4*)&xdblT[(size_t)k * BL + bl];
        float w = wreg[k];
        acc.x = fmaf(w, v.x, acc.x);
        acc.y = fmaf(w, v.y, acc.y);
        acc.z = fmaf(w, v.z, acc.z);
        acc.w = fmaf(w, v.w, acc.w);
    }
    float4 o;
    o.x = (acc.x > 20.f) ? acc.x : __logf(1.f + __expf(acc.x));
    o.y = (acc.y > 20.f) ? acc.y : __logf(1.f + __expf(acc.y));
    o.z = (acc.z > 20.f) ? acc.z : __logf(1.f + __expf(acc.z));
    o.w = (acc.w > 20.f) ? acc.w : __logf(1.f + __expf(acc.w));
    *(float4*)&deltaT[(size_t)d * BL + bl] = o;
}

// depthwise causal conv (k=4) + bias + SiLU, channel-major, 4 outputs/thread.
__global__ __launch_bounds__(256) void conv_silu(const float* __restrict__ xzT,
        const float* __restrict__ cw, const float* __restrict__ cb,
        float* __restrict__ uT)
{
    int i = blockIdx.x * 256 + threadIdx.x;     // over DI*BL/4
    int d  = i >> 10;
    int q  = i & 1023;
    int bl = q * 4;
    int l  = bl & (L_ - 1);
    const float* row = xzT + (size_t)d * BL;
    float4 cur = *(const float4*)&row[bl];
    float4 prev = make_float4(0.f, 0.f, 0.f, 0.f);
    if (l != 0) prev = *(const float4*)&row[bl - 4];
    float v[7] = { prev.y, prev.z, prev.w, cur.x, cur.y, cur.z, cur.w };
    float w0 = cw[d * 4 + 0], w1 = cw[d * 4 + 1], w2 = cw[d * 4 + 2], w3 = cw[d * 4 + 3];
    float bias = cb[d];
    float4 o;
    o.x = bias + w0 * v[0] + w1 * v[1] + w2 * v[2] + w3 * v[3];
    o.y = bias + w0 * v[1] + w1 * v[2] + w2 * v[3] + w3 * v[4];
    o.z = bias + w0 * v[2] + w1 * v[3] + w2 * v[4] + w3 * v[5];
    o.w = bias + w0 * v[3] + w1 * v[4] + w2 * v[5] + w3 * v[6];
    o.x = o.x / (1.f + __expf(-o.x));
    o.y = o.y / (1.f + __expf(-o.y));
    o.z = o.z / (1.f + __expf(-o.z));
    o.w = o.w / (1.f + __expf(-o.w));
    *(float4*)&uT[(size_t)d * BL + bl] = o;
}

// ---- selective scan v8: single-chunk, barrier-free, LDS-free ----
// Block = 4 waves = 4 (b,d); wave owns one (b,d). Lane k owns timesteps
// [16k, 16k+16); all 16 n-states live in registers.
//  - B/C read DIRECTLY from xdblT rows: lane reads its own 64B line; wave
//    covers 4KB contiguous -> line-coalesced, L2-resident (1 MB)
//  - phase 1: 16-step local affine summary; ONE Kogge-Stone shfl scan (6 rounds)
//  - phase 2: 16-step rescan + local C-contraction; gate; store
__global__ __launch_bounds__(256) void scan_fused(const float* __restrict__ deltaT,
        const float* __restrict__ uT, const float* __restrict__ xdblT,
        const float* __restrict__ xzT, const float* __restrict__ A_log,
        const float* __restrict__ Dp, float* __restrict__ yT)
{
    const int tid = threadIdx.x;
    const int lane = tid & 63;
    const int bd = blockIdx.x * 4 + (tid >> 6);
    const int d = bd & (DI - 1);
    const int b = bd >> 10;

    float Acoef[16];
    {
        const float4* ap = (const float4*)(A_log + d * NS);
        #pragma unroll
        for (int i = 0; i < 4; i++) {
            float4 v = ap[i];
            Acoef[i * 4 + 0] = -__expf(v.x); Acoef[i * 4 + 1] = -__expf(v.y);
            Acoef[i * 4 + 2] = -__expf(v.z); Acoef[i * 4 + 3] = -__expf(v.w);
        }
    }
    const float Dd = Dp[d];

    const size_t row_t = (size_t)d * BL + b * L_ + lane * 16;
    const size_t row_z = (size_t)(DI + d) * BL + b * L_ + lane * 16;
    const float* xB = xdblT + (size_t)32 * BL + b * L_ + lane * 16;  // B row n: +n*BL
    const float* xC = xdblT + (size_t)48 * BL + b * L_ + lane * 16;  // C row n: +n*BL

    // load 16 steps of delta, u (lane-contiguous 64B lines)
    float dv[16], uv[16];
    {
        const float4* dp = (const float4*)(deltaT + row_t);
        const float4* up = (const float4*)(uT + row_t);
        #pragma unroll
        for (int i = 0; i < 4; i++) {
            *(float4*)&dv[i * 4] = dp[i];
            *(float4*)&uv[i * 4] = up[i];
        }
    }
    float du[16];
    float sa = 0.f;
    #pragma unroll
    for (int j = 0; j < 16; j++) { du[j] = dv[j] * uv[j]; sa += dv[j]; }

    // ---- phase 1: local summary (a, bb) per n ----
    float a[16], bb[16];
    #pragma unroll
    for (int n = 0; n < 16; n++) {
        a[n] = __expf(sa * Acoef[n]);
        const float4* bp = (const float4*)(xB + (size_t)n * BL);
        float acc;
        #pragma unroll
        for (int i = 0; i < 4; i++) {
            float4 Bv = bp[i];
            if (i == 0) acc = du[0] * Bv.x;
            else        acc = fmaf(__expf(dv[i * 4] * Acoef[n]), acc, du[i * 4] * Bv.x);
            acc = fmaf(__expf(dv[i * 4 + 1] * Acoef[n]), acc, du[i * 4 + 1] * Bv.y);
            acc = fmaf(__expf(dv[i * 4 + 2] * Acoef[n]), acc, du[i * 4 + 2] * Bv.z);
            acc = fmaf(__expf(dv[i * 4 + 3] * Acoef[n]), acc, du[i * 4 + 3] * Bv.w);
        }
        bb[n] = acc;
    }

    // ---- ONE Kogge-Stone inclusive scan of affine maps over 64 lanes ----
    #pragma unroll
    for (int off = 1; off < 64; off <<= 1) {
        #pragma unroll
        for (int n = 0; n < 16; n++) {
            float pa = __shfl_up(a[n], off);
            float pb = __shfl_up(bb[n], off);
            if (lane >= off) {
                bb[n] = fmaf(a[n], pb, bb[n]);   // uses OLD a (newer ∘ older)
                a[n] *= pa;
            }
        }
    }

    // exclusive prefix -> h0 for this lane's 16 steps (global h0 = 0)
    float h[16];
    #pragma unroll
    for (int n = 0; n < 16; n++) {
        float pb = __shfl_up(bb[n], 1);
        h[n] = (lane == 0) ? 0.f : pb;
    }

    // ---- phase 2: rescan 16 steps + C-contraction ----
    float s[16];
    #pragma unroll
    for (int j = 0; j < 16; j++) s[j] = 0.f;
    #pragma unroll
    for (int n = 0; n < 16; n++) {
        const float4* bp = (const float4*)(xB + (size_t)n * BL);
        const float4* cp = (const float4*)(xC + (size_t)n * BL);
        float hn = h[n];
        #pragma unroll
        for (int i = 0; i < 4; i++) {
            float4 Bv = bp[i];
            float4 Cv = cp[i];
            hn = fmaf(__expf(dv[i * 4 + 0] * Acoef[n]), hn, du[i * 4 + 0] * Bv.x);
            s[i * 4 + 0] = fmaf(hn, Cv.x, s[i * 4 + 0]);
            hn = fmaf(__expf(dv[i * 4 + 1] * Acoef[n]), hn, du[i * 4 + 1] * Bv.y);
            s[i * 4 + 1] = fmaf(hn, Cv.y, s[i * 4 + 1]);
            hn = fmaf(__expf(dv[i * 4 + 2] * Acoef[n]), hn, du[i * 4 + 2] * Bv.z);
            s[i * 4 + 2] = fmaf(hn, Cv.z, s[i * 4 + 2]);
            hn = fmaf(__expf(dv[i * 4 + 3] * Acoef[n]), hn, du[i * 4 + 3] * Bv.w);
            s[i * 4 + 3] = fmaf(hn, Cv.w, s[i * 4 + 3]);
        }
    }

    // gate + store (lane-contiguous 64B lines)
    {
        const float4* zp = (const float4*)(xzT + row_z);
        float4* yp = (float4*)(yT + row_t);
        #pragma unroll
        for (int i = 0; i < 4; i++) {
            float4 zv = zp[i];
            float4 yv;
            float v0 = s[i * 4 + 0] + uv[i * 4 + 0] * Dd;
            float v1 = s[i * 4 + 1] + uv[i * 4 + 1] * Dd;
            float v2 = s[i * 4 + 2] + uv[i * 4 + 2] * Dd;
            float v3 = s[i * 4 + 3] + uv[i * 4 + 3] * Dd;
            yv.x = v0 * (zv.x / (1.f + __expf(-zv.x)));
            yv.y = v1 * (zv.y / (1.f + __expf(-zv.y)));
            yv.z = v2 * (zv.z / (1.f + __expf(-zv.z)));
            yv.w = v3 * (zv.w / (1.f + __expf(-zv.w)));
            yp[i] = yv;
        }
    }
}

// yT fp32 [DI][BL] -> yB bf16 [BL][DI], 64x64 LDS tiles.
__global__ __launch_bounds__(256) void transpose_cast(const float* __restrict__ yT,
        ushort* __restrict__ yB)
{
    __shared__ float t[64][65];
    const int bl0 = blockIdx.x * 64, d0 = blockIdx.y * 64;
    const int tid = threadIdx.x;
    #pragma unroll
    for (int i = 0; i < 4; i++) {
        int chunk = tid + i * 256;
        int dr = chunk >> 4, c4 = (chunk & 15) * 4;
        const float4 v = *(const float4*)&yT[(size_t)(d0 + dr) * BL + bl0 + c4];
        t[dr][c4 + 0] = v.x; t[dr][c4 + 1] = v.y;
        t[dr][c4 + 2] = v.z; t[dr][c4 + 3] = v.w;
    }
    __syncthreads();
    #pragma unroll
    for (int i = 0; i < 4; i++) {
        int chunk = tid + i * 256;
        int br = chunk >> 4, dc4 = (chunk & 15) * 4;
        ushort4 o;
        o.x = f2bf(t[dc4 + 0][br]); o.y = f2bf(t[dc4 + 1][br]);
        o.z = f2bf(t[dc4 + 2][br]); o.w = f2bf(t[dc4 + 3][br]);
        *(ushort4*)&yB[(size_t)(bl0 + br) * DI + d0 + dc4] = o;
    }
}

// LayerNorm over last dim (512), one block per row, fp32 out.
__global__ __launch_bounds__(256) void ln_kernel(const float* __restrict__ r,
        const float* __restrict__ lnw, const float* __restrict__ lnb,
        float* __restrict__ out)
{
    int row = blockIdx.x;
    const float* rr = r + (size_t)row * DM;
    float v0 = rr[threadIdx.x], v1 = rr[threadIdx.x + 256];
    float s = v0 + v1, s2 = v0 * v0 + v1 * v1;
    #pragma unroll
    for (int off = 32; off > 0; off >>= 1) {
        s  += __shfl_down(s, off);
        s2 += __shfl_down(s2, off);
    }
    __shared__ float ls[4], ls2[4];
    __shared__ float mu_s, rstd_s;
    int wid = threadIdx.x >> 6, lane = threadIdx.x & 63;
    if (lane == 0) { ls[wid] = s; ls2[wid] = s2; }
    __syncthreads();
    if (threadIdx.x == 0) {
        float S = ls[0] + ls[1] + ls[2] + ls[3];
        float S2 = ls2[0] + ls2[1] + ls2[2] + ls2[3];
        float mu = S * (1.f / DM);
        float var = S2 * (1.f / DM) - mu * mu;
        mu_s = mu;
        rstd_s = rsqrtf(var + 1e-5f);
    }
    __syncthreads();
    float mu = mu_s, rstd = rstd_s;
    out[(size_t)row * DM + threadIdx.x] =
        (v0 - mu) * rstd * lnw[threadIdx.x] + lnb[threadIdx.x];
    out[(size_t)row * DM + threadIdx.x + 256] =
        (v1 - mu) * rstd * lnw[threadIdx.x + 256] + lnb[threadIdx.x + 256];
}

extern "C" void kernel_launch(void* const* d_in, const int* in_sizes, int n_in,
                              void* d_out, int out_size, void* d_ws, size_t ws_size,
                              hipStream_t stream)
{
    const float* x         = (const float*)d_in[0];
    const float* in_proj_w = (const float*)d_in[1];
    const float* conv_w    = (const float*)d_in[2];
    const float* conv_b    = (const float*)d_in[3];
    const float* x_proj_w  = (const float*)d_in[4];
    const float* dt_proj_w = (const float*)d_in[5];
    const float* dt_proj_b = (const float*)d_in[6];
    const float* A_log     = (const float*)d_in[7];
    const float* Dvec      = (const float*)d_in[8];
    const float* out_proj_w= (const float*)d_in[9];
    const float* ln_w      = (const float*)d_in[10];
    const float* ln_b      = (const float*)d_in[11];
    float* out = (float*)d_out;

    // fp32 regions (floats)
    float* ws     = (float*)d_ws;
    float* xzT    = ws;                                  // 2048 x 4096 (32 MB)
    float* uT     = xzT    + (size_t)2048 * BL;          // 1024 x 4096 (16 MB)
    float* xdblT  = uT     + (size_t)DI * BL;            // 64 x 4096   (1 MB)
    float* deltaT = xdblT  + (size_t)XDC * BL;           // 1024 x 4096 (16 MB)
    float* yT     = deltaT + (size_t)DI * BL;            // 1024 x 4096 (16 MB)
    float* r      = yT     + (size_t)DI * BL;            // 4096 x 512  (8 MB)
    // aliases over time-dead regions:
    float*  xdblp = yT;                  // gemm3 partials (4 MB); written after xB dead
    ushort* yB    = (ushort*)deltaT;     // deltaT dead after scan
    ushort* xB    = (ushort*)yT;         // x bf16 (4 MB); dead after gemm1, before xdblp
    ushort* wInB  = (ushort*)deltaT;     // in_proj_w bf16 (2 MB); dead after gemm1
    ushort* wOutB = (ushort*)(r + (size_t)BL * DM);  // out_proj_w bf16 (1 MB); fresh space

    dim3 blk(256);

    // 0) pre-cast all bf16 operands in ONE launch
    cast3<<<(N4_X + N4_WIN + N4_WOUT + 255) / 256, blk, 0, stream>>>(
        x, xB, in_proj_w, wInB, out_proj_w, wOutB);

    // 1) xzT[e][bl] = in_proj_w @ x^T : M=2048, N=4096, K=512 (MFMA, bf16 staged)
    gemm_mfma<0, false, false><<<dim3(BL / 128, 2048 / 128), blk, 0, stream>>>(
        wInB, xB, xzT, DM, BL, nullptr);

    // 2) uT = silu(causal_conv(xsT) + cb)
    conv_silu<<<(DI * BL / 4) / 256, blk, 0, stream>>>(xzT, conv_w, conv_b, uT);

    // 3) xdblT = (u @ x_proj_w^T)^T : transposed split-K partials + reduce
    gemm3_splitk<<<dim3(KS, BL / 32), blk, 0, stream>>>(uT, x_proj_w, xdblp);
    gemm3_reduce<<<(64 * BL / 4) / 256, blk, 0, stream>>>(xdblp, xdblT);

    // 4) deltaT[d][bl] = softplus(dtw[d] . xdblT[0:32][bl] + b) : coalesced gemv
    dt_softplus<<<dim3(BL / 256, DI / 4), blk, 0, stream>>>(
        xdblT, dt_proj_w, dt_proj_b, deltaT);

    // 5) fused selective scan + gate (single-chunk, wave-independent)
    scan_fused<<<B_ * DI / 4, blk, 0, stream>>>(
        deltaT, uT, xdblT, xzT, A_log, Dvec, yT);

    // 6a) yT -> yB (bf16, [bl][d])
    transpose_cast<<<dim3(BL / 64, DI / 64), blk, 0, stream>>>(yT, yB);

    // 6b) r[bl][dm] = y @ out_proj_w^T + x : M=4096, N=512, K=1024
    //     (MFMA 128x64 tile -> 256 blocks = full CU coverage, resid epi)
    gemm_mfma_n64<2, false, false><<<dim3(DM / 64, BL / 128), blk, 0, stream>>>(
        yB, wOutB, r, DI, DM, x);

    // 7) LayerNorm -> fp32 out
    ln_kernel<<<BL, blk, 0, stream>>>(r, ln_w, ln_b, out);
}

// Round 16
// 244.471 us; speedup vs baseline: 1.2044x; 1.0105x over previous
//
#include <hip/hip_runtime.h>
#include <hip/hip_bf16.h>
#include <math.h>

// MambaBlock: B=4, L=1024, D_MODEL=512, D_INNER=1024, D_STATE=16, D_CONV=4, DT_RANK=32
// fp32 in/out. 10 dispatches:
//  cast3 (all bf16 operand pre-casts in ONE launch) ->
//  gemm1 (MFMA 128x128, global_load_lds 16B staging) -> conv_silu ->
//  gemm3 splitk (b128 LDS) + reduce (TRANSPOSED xdblT [64][BL], L2-resident) ->
//  dt_softplus -> scan v8 (single-chunk, lane owns 16 steps, ONE Kogge-Stone,
//  no LDS/barriers) -> transpose_cast ->
//  gemm6 (MFMA 128x64, global_load_lds staging, 256 blocks = 1/CU) -> LN.
#define B_   4
#define L_   1024
#define DM   512
#define DI   1024
#define NS   16
#define XDC  64      // DT_RANK + 2*D_STATE
#define BL   4096    // B_*L_
#define KS   4       // gemm3 split-K factor

typedef short bfrag __attribute__((ext_vector_type(8)));   // 8 bf16
typedef float ffrag __attribute__((ext_vector_type(4)));   // 4 fp32 acc

__device__ __forceinline__ ushort f2bf(float v) {
    __hip_bfloat16 h = __float2bfloat16(v);
    return *(ushort*)&h;
}

// async global->LDS, 16B per lane (wave writes 1KB linear: base + lane*16)
__device__ __forceinline__ void gload_lds16(const ushort* g, ushort* l) {
    __builtin_amdgcn_global_load_lds(
        (const __attribute__((address_space(1))) unsigned int*)g,
        (__attribute__((address_space(3))) unsigned int*)l, 16, 0, 0);
}

#define N4_X   (BL * DM / 4)        // 524288
#define N4_WIN (2048 * DM / 4)      // 262144
#define N4_WOUT (DM * DI / 4)       // 131072

// one-launch fp32->bf16 pre-cast of x, in_proj_w, out_proj_w (4 elems/thread)
__global__ __launch_bounds__(256) void cast3(const float* __restrict__ x,
        ushort* __restrict__ xB, const float* __restrict__ win,
        ushort* __restrict__ wInB, const float* __restrict__ wout,
        ushort* __restrict__ wOutB)
{
    int i = blockIdx.x * 256 + threadIdx.x;
    const float* src; ushort* dst; int j;
    if (i < N4_X)                   { src = x;    dst = xB;    j = i; }
    else if (i < N4_X + N4_WIN)     { src = win;  dst = wInB;  j = i - N4_X; }
    else if (i < N4_X + N4_WIN + N4_WOUT) { src = wout; dst = wOutB; j = i - N4_X - N4_WIN; }
    else return;
    float4 v = ((const float4*)src)[j];
    ushort4 o;
    o.x = f2bf(v.x); o.y = f2bf(v.y); o.z = f2bf(v.z); o.w = f2bf(v.w);
    ((ushort4*)dst)[j] = o;
}

// MFMA bf16 TN GEMM: C[M,N] = A[M,K] * B[N,K]^T, fp32 out.
// 128x128 block tile, BK=32, 4 waves (2x2), wave tile 64x64 (4x4 of 16x16x32).
// Staging via global_load_lds (async DMA, no VGPR round-trip). LDS linear
// [128][32] (chunk*16B = &As[chunk>>2][(chunk&3)*8]) -- required by the DMA's
// base+lane*16 write pattern; the ~8-way fragment-read bank conflict this
// reintroduces is the m97-measured tradeoff and is far cheaper than VALU staging.
// EPI: 0 none; 2 C += resid[m*ldc+n]
template<int EPI>
__global__ __launch_bounds__(256) void gemm_mfma(const ushort* __restrict__ A,
        const ushort* __restrict__ B, float* __restrict__ C,
        int K, int ldc, const float* __restrict__ resid)
{
    __shared__ ushort As[128][32];
    __shared__ ushort Bs[128][32];
    const int tid = threadIdx.x;
    const int lane = tid & 63, wave = tid >> 6;
    const int wm = (wave & 1) * 64, wn = (wave >> 1) * 64;
    const int l15 = lane & 15, quad = lane >> 4;
    const int m0 = blockIdx.y * 128, n0 = blockIdx.x * 128;

    ffrag acc[4][4] = {};

    for (int k0 = 0; k0 < K; k0 += 32) {
        #pragma unroll
        for (int i = 0; i < 2; i++) {
            int chunk = tid + i * 256;
            int row = chunk >> 2, kk8 = (chunk & 3) * 8;
            gload_lds16(&A[(size_t)(m0 + row) * K + k0 + kk8], &As[0][0] + chunk * 8);
            gload_lds16(&B[(size_t)(n0 + row) * K + k0 + kk8], &Bs[0][0] + chunk * 8);
        }
        __syncthreads();
        bfrag af[4], bfv[4];
        #pragma unroll
        for (int i = 0; i < 4; i++) {
            af[i]  = *(const bfrag*)&As[wm + i * 16 + l15][quad * 8];
            bfv[i] = *(const bfrag*)&Bs[wn + i * 16 + l15][quad * 8];
        }
        #pragma unroll
        for (int i = 0; i < 4; i++)
            #pragma unroll
            for (int j = 0; j < 4; j++)
                acc[i][j] = __builtin_amdgcn_mfma_f32_16x16x32_bf16(af[i], bfv[j], acc[i][j], 0, 0, 0);
        __syncthreads();
    }

    #pragma unroll
    for (int i = 0; i < 4; i++) {
        #pragma unroll
        for (int j = 0; j < 4; j++) {
            int n = n0 + wn + j * 16 + l15;
            #pragma unroll
            for (int r = 0; r < 4; r++) {
                int m = m0 + wm + i * 16 + quad * 4 + r;
                float v = acc[i][j][r];
                if (EPI == 2) v += resid[(size_t)m * ldc + n];
                C[(size_t)m * ldc + n] = v;
            }
        }
    }
}

// MFMA bf16 TN GEMM, 128x64 tile (N=512 outputs: grid 8x32 = 256 blocks = 1/CU).
// 4 waves 2x2, wave tile 64x32 (4x2 of 16x16x32). global_load_lds staging.
template<int EPI>
__global__ __launch_bounds__(256) void gemm_mfma_n64(const ushort* __restrict__ A,
        const ushort* __restrict__ B, float* __restrict__ C,
        int K, int ldc, const float* __restrict__ resid)
{
    __shared__ ushort As[128][32];
    __shared__ ushort Bs[64][32];
    const int tid = threadIdx.x;
    const int lane = tid & 63, wave = tid >> 6;
    const int wm = (wave & 1) * 64, wn = (wave >> 1) * 32;
    const int l15 = lane & 15, quad = lane >> 4;
    const int m0 = blockIdx.y * 128, n0 = blockIdx.x * 64;

    ffrag acc[4][2] = {};

    for (int k0 = 0; k0 < K; k0 += 32) {
        #pragma unroll
        for (int i = 0; i < 2; i++) {
            int chunk = tid + i * 256;
            int row = chunk >> 2, kk8 = (chunk & 3) * 8;
            gload_lds16(&A[(size_t)(m0 + row) * K + k0 + kk8], &As[0][0] + chunk * 8);
        }
        {
            int row = tid >> 2, kk8 = (tid & 3) * 8;
            gload_lds16(&B[(size_t)(n0 + row) * K + k0 + kk8], &Bs[0][0] + tid * 8);
        }
        __syncthreads();
        bfrag af[4], bfv[2];
        #pragma unroll
        for (int i = 0; i < 4; i++)
            af[i] = *(const bfrag*)&As[wm + i * 16 + l15][quad * 8];
        #pragma unroll
        for (int j = 0; j < 2; j++)
            bfv[j] = *(const bfrag*)&Bs[wn + j * 16 + l15][quad * 8];
        #pragma unroll
        for (int i = 0; i < 4; i++)
            #pragma unroll
            for (int j = 0; j < 2; j++)
                acc[i][j] = __builtin_amdgcn_mfma_f32_16x16x32_bf16(af[i], bfv[j], acc[i][j], 0, 0, 0);
        __syncthreads();
    }

    #pragma unroll
    for (int i = 0; i < 4; i++) {
        #pragma unroll
        for (int j = 0; j < 2; j++) {
            int n = n0 + wn + j * 16 + l15;
            #pragma unroll
            for (int r = 0; r < 4; r++) {
                int m = m0 + wm + i * 16 + quad * 4 + r;
                float v = acc[i][j][r];
                if (EPI == 2) v += resid[(size_t)m * ldc + n];
                C[(size_t)m * ldc + n] = v;
            }
        }
    }
}

// gemm3 split-K, TRANSPOSED output: part[ks][n][m] = sum over K-chunk of u[m][k]*W[n][k].
// A = uT [K=DI][M=BL], W = x_proj_w [64][DI].
// Block: 32 m-rows x 64 n-cols, K-chunk = DI/KS = 256, BK=16.
// As stride 36 floats (144B, 16B-aligned rows) so the wave-uniform A reads are
// 2x ds_read_b128: inner loop 3 LDS reads + 8 fma.
__global__ __launch_bounds__(256) void gemm3_splitk(const float* __restrict__ uT,
        const float* __restrict__ xw, float* __restrict__ part)
{
    __shared__ float As[16][36];    // [k][m] 32 m, 16B-aligned rows
    __shared__ float Ws[16][68];    // [k][n] 64 n
    const int tid = threadIdx.x;
    const int nn = tid & 63;
    const int mg = tid >> 6;        // 0..3
    const int ks = blockIdx.x, m0 = blockIdx.y * 32;
    const int kbase = ks * (DI / KS);
    float acc[8] = {};

    for (int k0 = 0; k0 < DI / KS; k0 += 16) {
        if (tid < 128) {
            int k = tid >> 3, m4 = (tid & 7) * 4;
            const float4 v = *(const float4*)&uT[(size_t)(kbase + k0 + k) * BL + m0 + m4];
            *(float4*)&As[k][m4] = v;
        }
        {
            int r = tid >> 2, c4 = (tid & 3) * 4;
            const float4 v = *(const float4*)&xw[(size_t)r * DI + kbase + k0 + c4];
            Ws[c4 + 0][r] = v.x; Ws[c4 + 1][r] = v.y;
            Ws[c4 + 2][r] = v.z; Ws[c4 + 3][r] = v.w;
        }
        __syncthreads();
        #pragma unroll
        for (int kk = 0; kk < 16; kk++) {
            float w = Ws[kk][nn];
            float4 a0 = *(const float4*)&As[kk][mg * 8];
            float4 a1 = *(const float4*)&As[kk][mg * 8 + 4];
            acc[0] = fmaf(a0.x, w, acc[0]);
            acc[1] = fmaf(a0.y, w, acc[1]);
            acc[2] = fmaf(a0.z, w, acc[2]);
            acc[3] = fmaf(a0.w, w, acc[3]);
            acc[4] = fmaf(a1.x, w, acc[4]);
            acc[5] = fmaf(a1.y, w, acc[5]);
            acc[6] = fmaf(a1.z, w, acc[6]);
            acc[7] = fmaf(a1.w, w, acc[7]);
        }
        __syncthreads();
    }

    float* pp = part + (size_t)ks * 64 * BL + (size_t)nn * BL + m0 + mg * 8;
    *(float4*)&pp[0] = make_float4(acc[0], acc[1], acc[2], acc[3]);
    *(float4*)&pp[4] = make_float4(acc[4], acc[5], acc[6], acc[7]);
}

// reduce KS transposed partials -> xdblT [64][BL] fp32.
__global__ __launch_bounds__(256) void gemm3_reduce(const float* __restrict__ part,
        float* __restrict__ xdblT)
{
    int i = blockIdx.x * 256 + threadIdx.x;     // over 64*BL/4
    const float4* p0 = (const float4*)part;
    float4 a = p0[i];
    #pragma unroll
    for (int s = 1; s < KS; s++) {
        float4 b = p0[i + (size_t)s * 64 * BL / 4];
        a.x += b.x; a.y += b.y; a.z += b.z; a.w += b.w;
    }
    ((float4*)xdblT)[i] = a;
}

// delta[d][bl] = softplus(sum_k dtw[d][k] * xdblT[k][bl] + bias[d])
// Block: 4 waves; wave w owns d = blockIdx.y*4 + w. Thread owns one float4 of bl.
__global__ __launch_bounds__(256) void dt_softplus(const float* __restrict__ xdblT,
        const float* __restrict__ dtw, const float* __restrict__ bias,
        float* __restrict__ deltaT)
{
    const int tid = threadIdx.x;
    const int lane = tid & 63;
    const int bl = blockIdx.x * 256 + lane * 4;

    int d = blockIdx.y * 4 + (tid >> 6);
    d = __builtin_amdgcn_readfirstlane(d);
    float wreg[32];
    {
        const float4* wp = (const float4*)(dtw + (size_t)d * 32);
        #pragma unroll
        for (int k = 0; k < 8; k++) *(float4*)&wreg[k * 4] = wp[k];
    }
    const float bb = bias[d];

    float4 acc = make_float4(bb, bb, bb, bb);
    #pragma unroll
    for (int k = 0; k < 32; k++) {
        float4 v = *(const float4*)&xdblT[(size_t)k * BL + bl];
        float w = wreg[k];
        acc.x = fmaf(w, v.x, acc.x);
        acc.y = fmaf(w, v.y, acc.y);
        acc.z = fmaf(w, v.z, acc.z);
        acc.w = fmaf(w, v.w, acc.w);
    }
    float4 o;
    o.x = (acc.x > 20.f) ? acc.x : __logf(1.f + __expf(acc.x));
    o.y = (acc.y > 20.f) ? acc.y : __logf(1.f + __expf(acc.y));
    o.z = (acc.z > 20.f) ? acc.z : __logf(1.f + __expf(acc.z));
    o.w = (acc.w > 20.f) ? acc.w : __logf(1.f + __expf(acc.w));
    *(float4*)&deltaT[(size_t)d * BL + bl] = o;
}

// depthwise causal conv (k=4) + bias + SiLU, channel-major, 4 outputs/thread.
__global__ __launch_bounds__(256) void conv_silu(const float* __restrict__ xzT,
        const float* __restrict__ cw, const float* __restrict__ cb,
        float* __restrict__ uT)
{
    int i = blockIdx.x * 256 + threadIdx.x;     // over DI*BL/4
    int d  = i >> 10;
    int q  = i & 1023;
    int bl = q * 4;
    int l  = bl & (L_ - 1);
    const float* row = xzT + (size_t)d * BL;
    float4 cur = *(const float4*)&row[bl];
    float4 prev = make_float4(0.f, 0.f, 0.f, 0.f);
    if (l != 0) prev = *(const float4*)&row[bl - 4];
    float v[7] = { prev.y, prev.z, prev.w, cur.x, cur.y, cur.z, cur.w };
    float w0 = cw[d * 4 + 0], w1 = cw[d * 4 + 1], w2 = cw[d * 4 + 2], w3 = cw[d * 4 + 3];
    float bias = cb[d];
    float4 o;
    o.x = bias + w0 * v[0] + w1 * v[1] + w2 * v[2] + w3 * v[3];
    o.y = bias + w0 * v[1] + w1 * v[2] + w2 * v[3] + w3 * v[4];
    o.z = bias + w0 * v[2] + w1 * v[3] + w2 * v[4] + w3 * v[5];
    o.w = bias + w0 * v[3] + w1 * v[4] + w2 * v[5] + w3 * v[6];
    o.x = o.x / (1.f + __expf(-o.x));
    o.y = o.y / (1.f + __expf(-o.y));
    o.z = o.z / (1.f + __expf(-o.z));
    o.w = o.w / (1.f + __expf(-o.w));
    *(float4*)&uT[(size_t)d * BL + bl] = o;
}

// ---- selective scan v8: single-chunk, barrier-free, LDS-free ----
// Block = 4 waves = 4 (b,d); wave owns one (b,d). Lane k owns timesteps
// [16k, 16k+16); all 16 n-states live in registers.
//  - B/C read DIRECTLY from xdblT rows: lane reads its own 64B line; wave
//    covers 4KB contiguous -> line-coalesced, L2-resident (1 MB)
//  - phase 1: 16-step local affine summary; ONE Kogge-Stone shfl scan (6 rounds)
//  - phase 2: 16-step rescan + local C-contraction; gate; store
__global__ __launch_bounds__(256) void scan_fused(const float* __restrict__ deltaT,
        const float* __restrict__ uT, const float* __restrict__ xdblT,
        const float* __restrict__ xzT, const float* __restrict__ A_log,
        const float* __restrict__ Dp, float* __restrict__ yT)
{
    const int tid = threadIdx.x;
    const int lane = tid & 63;
    const int bd = blockIdx.x * 4 + (tid >> 6);
    const int d = bd & (DI - 1);
    const int b = bd >> 10;

    float Acoef[16];
    {
        const float4* ap = (const float4*)(A_log + d * NS);
        #pragma unroll
        for (int i = 0; i < 4; i++) {
            float4 v = ap[i];
            Acoef[i * 4 + 0] = -__expf(v.x); Acoef[i * 4 + 1] = -__expf(v.y);
            Acoef[i * 4 + 2] = -__expf(v.z); Acoef[i * 4 + 3] = -__expf(v.w);
        }
    }
    const float Dd = Dp[d];

    const size_t row_t = (size_t)d * BL + b * L_ + lane * 16;
    const size_t row_z = (size_t)(DI + d) * BL + b * L_ + lane * 16;
    const float* xB = xdblT + (size_t)32 * BL + b * L_ + lane * 16;  // B row n: +n*BL
    const float* xC = xdblT + (size_t)48 * BL + b * L_ + lane * 16;  // C row n: +n*BL

    // load 16 steps of delta, u (lane-contiguous 64B lines)
    float dv[16], uv[16];
    {
        const float4* dp = (const float4*)(deltaT + row_t);
        const float4* up = (const float4*)(uT + row_t);
        #pragma unroll
        for (int i = 0; i < 4; i++) {
            *(float4*)&dv[i * 4] = dp[i];
            *(float4*)&uv[i * 4] = up[i];
        }
    }
    float du[16];
    float sa = 0.f;
    #pragma unroll
    for (int j = 0; j < 16; j++) { du[j] = dv[j] * uv[j]; sa += dv[j]; }

    // ---- phase 1: local summary (a, bb) per n ----
    float a[16], bb[16];
    #pragma unroll
    for (int n = 0; n < 16; n++) {
        a[n] = __expf(sa * Acoef[n]);
        const float4* bp = (const float4*)(xB + (size_t)n * BL);
        float acc;
        #pragma unroll
        for (int i = 0; i < 4; i++) {
            float4 Bv = bp[i];
            if (i == 0) acc = du[0] * Bv.x;
            else        acc = fmaf(__expf(dv[i * 4] * Acoef[n]), acc, du[i * 4] * Bv.x);
            acc = fmaf(__expf(dv[i * 4 + 1] * Acoef[n]), acc, du[i * 4 + 1] * Bv.y);
            acc = fmaf(__expf(dv[i * 4 + 2] * Acoef[n]), acc, du[i * 4 + 2] * Bv.z);
            acc = fmaf(__expf(dv[i * 4 + 3] * Acoef[n]), acc, du[i * 4 + 3] * Bv.w);
        }
        bb[n] = acc;
    }

    // ---- ONE Kogge-Stone inclusive scan of affine maps over 64 lanes ----
    #pragma unroll
    for (int off = 1; off < 64; off <<= 1) {
        #pragma unroll
        for (int n = 0; n < 16; n++) {
            float pa = __shfl_up(a[n], off);
            float pb = __shfl_up(bb[n], off);
            if (lane >= off) {
                bb[n] = fmaf(a[n], pb, bb[n]);   // uses OLD a (newer ∘ older)
                a[n] *= pa;
            }
        }
    }

    // exclusive prefix -> h0 for this lane's 16 steps (global h0 = 0)
    float h[16];
    #pragma unroll
    for (int n = 0; n < 16; n++) {
        float pb = __shfl_up(bb[n], 1);
        h[n] = (lane == 0) ? 0.f : pb;
    }

    // ---- phase 2: rescan 16 steps + C-contraction ----
    float s[16];
    #pragma unroll
    for (int j = 0; j < 16; j++) s[j] = 0.f;
    #pragma unroll
    for (int n = 0; n < 16; n++) {
        const float4* bp = (const float4*)(xB + (size_t)n * BL);
        const float4* cp = (const float4*)(xC + (size_t)n * BL);
        float hn = h[n];
        #pragma unroll
        for (int i = 0; i < 4; i++) {
            float4 Bv = bp[i];
            float4 Cv = cp[i];
            hn = fmaf(__expf(dv[i * 4 + 0] * Acoef[n]), hn, du[i * 4 + 0] * Bv.x);
            s[i * 4 + 0] = fmaf(hn, Cv.x, s[i * 4 + 0]);
            hn = fmaf(__expf(dv[i * 4 + 1] * Acoef[n]), hn, du[i * 4 + 1] * Bv.y);
            s[i * 4 + 1] = fmaf(hn, Cv.y, s[i * 4 + 1]);
            hn = fmaf(__expf(dv[i * 4 + 2] * Acoef[n]), hn, du[i * 4 + 2] * Bv.z);
            s[i * 4 + 2] = fmaf(hn, Cv.z, s[i * 4 + 2]);
            hn = fmaf(__expf(dv[i * 4 + 3] * Acoef[n]), hn, du[i * 4 + 3] * Bv.w);
            s[i * 4 + 3] = fmaf(hn, Cv.w, s[i * 4 + 3]);
        }
    }

    // gate + store (lane-contiguous 64B lines)
    {
        const float4* zp = (const float4*)(xzT + row_z);
        float4* yp = (float4*)(yT + row_t);
        #pragma unroll
        for (int i = 0; i < 4; i++) {
            float4 zv = zp[i];
            float4 yv;
            float v0 = s[i * 4 + 0] + uv[i * 4 + 0] * Dd;
            float v1 = s[i * 4 + 1] + uv[i * 4 + 1] * Dd;
            float v2 = s[i * 4 + 2] + uv[i * 4 + 2] * Dd;
            float v3 = s[i * 4 + 3] + uv[i * 4 + 3] * Dd;
            yv.x = v0 * (zv.x / (1.f + __expf(-zv.x)));
            yv.y = v1 * (zv.y / (1.f + __expf(-zv.y)));
            yv.z = v2 * (zv.z / (1.f + __expf(-zv.z)));
            yv.w = v3 * (zv.w / (1.f + __expf(-zv.w)));
            yp[i] = yv;
        }
    }
}

// yT fp32 [DI][BL] -> yB bf16 [BL][DI], 64x64 LDS tiles.
__global__ __launch_bounds__(256) void transpose_cast(const float* __restrict__ yT,
        ushort* __restrict__ yB)
{
    __shared__ float t[64][65];
    const int bl0 = blockIdx.x * 64, d0 = blockIdx.y * 64;
    const int tid = threadIdx.x;
    #pragma unroll
    for (int i = 0; i < 4; i++) {
        int chunk = tid + i * 256;
        int dr = chunk >> 4, c4 = (chunk & 15) * 4;
        const float4 v = *(const float4*)&yT[(size_t)(d0 + dr) * BL + bl0 + c4];
        t[dr][c4 + 0] = v.x; t[dr][c4 + 1] = v.y;
        t[dr][c4 + 2] = v.z; t[dr][c4 + 3] = v.w;
    }
    __syncthreads();
    #pragma unroll
    for (int i = 0; i < 4; i++) {
        int chunk = tid + i * 256;
        int br = chunk >> 4, dc4 = (chunk & 15) * 4;
        ushort4 o;
        o.x = f2bf(t[dc4 + 0][br]); o.y = f2bf(t[dc4 + 1][br]);
        o.z = f2bf(t[dc4 + 2][br]); o.w = f2bf(t[dc4 + 3][br]);
        *(ushort4*)&yB[(size_t)(bl0 + br) * DI + d0 + dc4] = o;
    }
}

// LayerNorm over last dim (512), one block per row, fp32 out.
__global__ __launch_bounds__(256) void ln_kernel(const float* __restrict__ r,
        const float* __restrict__ lnw, const float* __restrict__ lnb,
        float* __restrict__ out)
{
    int row = blockIdx.x;
    const float* rr = r + (size_t)row * DM;
    float v0 = rr[threadIdx.x], v1 = rr[threadIdx.x + 256];
    float s = v0 + v1, s2 = v0 * v0 + v1 * v1;
    #pragma unroll
    for (int off = 32; off > 0; off >>= 1) {
        s  += __shfl_down(s, off);
        s2 += __shfl_down(s2, off);
    }
    __shared__ float ls[4], ls2[4];
    __shared__ float mu_s, rstd_s;
    int wid = threadIdx.x >> 6, lane = threadIdx.x & 63;
    if (lane == 0) { ls[wid] = s; ls2[wid] = s2; }
    __syncthreads();
    if (threadIdx.x == 0) {
        float S = ls[0] + ls[1] + ls[2] + ls[3];
        float S2 = ls2[0] + ls2[1] + ls2[2] + ls2[3];
        float mu = S * (1.f / DM);
        float var = S2 * (1.f / DM) - mu * mu;
        mu_s = mu;
        rstd_s = rsqrtf(var + 1e-5f);
    }
    __syncthreads();
    float mu = mu_s, rstd = rstd_s;
    out[(size_t)row * DM + threadIdx.x] =
        (v0 - mu) * rstd * lnw[threadIdx.x] + lnb[threadIdx.x];
    out[(size_t)row * DM + threadIdx.x + 256] =
        (v1 - mu) * rstd * lnw[threadIdx.x + 256] + lnb[threadIdx.x + 256];
}

extern "C" void kernel_launch(void* const* d_in, const int* in_sizes, int n_in,
                              void* d_out, int out_size, void* d_ws, size_t ws_size,
                              hipStream_t stream)
{
    const float* x         = (const float*)d_in[0];
    const float* in_proj_w = (const float*)d_in[1];
    const float* conv_w    = (const float*)d_in[2];
    const float* conv_b    = (const float*)d_in[3];
    const float* x_proj_w  = (const float*)d_in[4];
    const float* dt_proj_w = (const float*)d_in[5];
    const float* dt_proj_b = (const float*)d_in[6];
    const float* A_log     = (const float*)d_in[7];
    const float* Dvec      = (const float*)d_in[8];
    const float* out_proj_w= (const float*)d_in[9];
    const float* ln_w      = (const float*)d_in[10];
    const float* ln_b      = (const float*)d_in[11];
    float* out = (float*)d_out;

    // fp32 regions (floats)
    float* ws     = (float*)d_ws;
    float* xzT    = ws;                                  // 2048 x 4096 (32 MB)
    float* uT     = xzT    + (size_t)2048 * BL;          // 1024 x 4096 (16 MB)
    float* xdblT  = uT     + (size_t)DI * BL;            // 64 x 4096   (1 MB)
    float* deltaT = xdblT  + (size_t)XDC * BL;           // 1024 x 4096 (16 MB)
    float* yT     = deltaT + (size_t)DI * BL;            // 1024 x 4096 (16 MB)
    float* r      = yT     + (size_t)DI * BL;            // 4096 x 512  (8 MB)
    // aliases over time-dead regions:
    float*  xdblp = yT;                  // gemm3 partials (4 MB); written after xB dead
    ushort* yB    = (ushort*)deltaT;     // deltaT dead after scan
    ushort* xB    = (ushort*)yT;         // x bf16 (4 MB); dead after gemm1, before xdblp
    ushort* wInB  = (ushort*)deltaT;     // in_proj_w bf16 (2 MB); dead after gemm1
    ushort* wOutB = (ushort*)(r + (size_t)BL * DM);  // out_proj_w bf16 (1 MB); fresh space

    dim3 blk(256);

    // 0) pre-cast all bf16 operands in ONE launch
    cast3<<<(N4_X + N4_WIN + N4_WOUT + 255) / 256, blk, 0, stream>>>(
        x, xB, in_proj_w, wInB, out_proj_w, wOutB);

    // 1) xzT[e][bl] = in_proj_w @ x^T : M=2048, N=4096, K=512 (MFMA, async staging)
    gemm_mfma<0><<<dim3(BL / 128, 2048 / 128), blk, 0, stream>>>(
        wInB, xB, xzT, DM, BL, nullptr);

    // 2) uT = silu(causal_conv(xsT) + cb)
    conv_silu<<<(DI * BL / 4) / 256, blk, 0, stream>>>(xzT, conv_w, conv_b, uT);

    // 3) xdblT = (u @ x_proj_w^T)^T : transposed split-K partials + reduce
    gemm3_splitk<<<dim3(KS, BL / 32), blk, 0, stream>>>(uT, x_proj_w, xdblp);
    gemm3_reduce<<<(64 * BL / 4) / 256, blk, 0, stream>>>(xdblp, xdblT);

    // 4) deltaT[d][bl] = softplus(dtw[d] . xdblT[0:32][bl] + b) : coalesced gemv
    dt_softplus<<<dim3(BL / 256, DI / 4), blk, 0, stream>>>(
        xdblT, dt_proj_w, dt_proj_b, deltaT);

    // 5) fused selective scan + gate (single-chunk, wave-independent)
    scan_fused<<<B_ * DI / 4, blk, 0, stream>>>(
        deltaT, uT, xdblT, xzT, A_log, Dvec, yT);

    // 6a) yT -> yB (bf16, [bl][d])
    transpose_cast<<<dim3(BL / 64, DI / 64), blk, 0, stream>>>(yT, yB);

    // 6b) r[bl][dm] = y @ out_proj_w^T + x : M=4096, N=512, K=1024
    //     (MFMA 128x64 tile, async staging, resid epi)
    gemm_mfma_n64<2><<<dim3(DM / 64, BL / 128), blk, 0, stream>>>(
        yB, wOutB, r, DI, DM, x);

    // 7) LayerNorm -> fp32 out
    ln_kernel<<<BL, blk, 0, stream>>>(r, ln_w, ln_b, out);
}